// Round 1
// baseline (214.746 us; speedup 1.0000x reference)
//
#include <hip/hip_runtime.h>
#include <hip/hip_bf16.h>
#include <math.h>

// DirectVoxGO fused forward. 1 block = 1 ray (128 points), 256 threads (4 waves).
// Phase A: grid gathers (f32) -> alpha out + bf16 feature tile in LDS.
// Phase B/C: MFMA bf16 GEMMs (K padded 39->64), XOR-swizzled LDS tiles.
// Phase D: layer3 (N=3) on VALU from accumulators, shfl reduce, sigmoid.

typedef __bf16 bf16x8 __attribute__((ext_vector_type(8)));
typedef float  f32x4  __attribute__((ext_vector_type(4)));

#define ACT_SHIFT_F (-13.815509557964774f)

// LDS byte offsets (total exactly 65536 B -> 2 blocks/CU)
#define H1_OFF   0       // h1 [128][128] bf16, stride 256 B, swizzled
#define SA_OFF   32768   // feature tile [128][64] bf16, stride 128 B, swizzled
#define SW1_OFF  49152   // w1^T [n=128][k=64] bf16, stride 128 B, swizzled
#define SW2_OFF  32768   // w2^T [n=128][k=128] bf16, stride 256 B, swizzled (reuses SA/SW1 space)

#define STA(row_, col_, val_) do { \
    int _a = SA_OFF + (row_)*128 + (col_)*2; _a ^= (((row_) & 7) << 4); \
    *reinterpret_cast<__bf16*>(smem + _a) = (__bf16)(val_); } while (0)

__global__ __launch_bounds__(256, 2)
void dvgo_fused(const float* __restrict__ g_org, const float* __restrict__ g_dir,
                const float* __restrict__ g_len, const float* __restrict__ g_gd,
                const float* __restrict__ g_gc, const float* __restrict__ g_w1,
                const float* __restrict__ g_b1, const float* __restrict__ g_w2,
                const float* __restrict__ g_b2, const float* __restrict__ g_w3,
                const float* __restrict__ g_b3,
                float* __restrict__ out_alpha, float* __restrict__ out_rgb)
{
    __shared__ __align__(16) char smem[65536];
    const int tid = threadIdx.x;
    const int ray = blockIdx.x;

    const float o0 = g_org[ray*3+0], o1 = g_org[ray*3+1], o2 = g_org[ray*3+2];
    const float d0 = g_dir[ray*3+0], d1 = g_dir[ray*3+1], d2 = g_dir[ray*3+2];

    // ---- stage w1 -> sW1t[n][k], k zero-padded to 64, bf16, swizzled ----
    for (int idx = tid; idx < 64*128; idx += 256) {
        const int kk = idx >> 7, n = idx & 127;
        const float v = (kk < 39) ? g_w1[kk*128 + n] : 0.0f;   // coalesced read
        int a = SW1_OFF + n*128 + kk*2; a ^= ((n & 7) << 4);
        *reinterpret_cast<__bf16*>(smem + a) = (__bf16)v;
    }

    // ---- phase A ----
    if (tid < 128) {
        const int p = tid;
        const float len = g_len[ray*128 + p];
        const float px = (o0 + d0*len + 1.0f) * 49.5f;
        const float py = (o1 + d1*len + 1.0f) * 49.5f;
        const float pz = (o2 + d2*len + 1.0f) * 49.5f;
        float fx = floorf(px), fy = floorf(py), fz = floorf(pz);
        const int ix = (int)fx, iy = (int)fy, iz = (int)fz;
        const float qx = px - fx, qy = py - fy, qz = pz - fz;
        const float wxa[2] = {1.0f - qx, qx};
        const float wya[2] = {1.0f - qy, qy};
        const float wza[2] = {1.0f - qz, qz};
        const int  cxa[2] = {min(max(ix,0),99),   min(max(ix+1,0),99)};
        const int  cya[2] = {min(max(iy,0),99),   min(max(iy+1,0),99)};
        const int  cza[2] = {min(max(iz,0),99),   min(max(iz+1,0),99)};
        const bool vxa[2] = {(unsigned)ix < 100u, (unsigned)(ix+1) < 100u};
        const bool vya[2] = {(unsigned)iy < 100u, (unsigned)(iy+1) < 100u};
        const bool vza[2] = {(unsigned)iz < 100u, (unsigned)(iz+1) < 100u};

        float den = 0.0f;
        float cc[12];
        #pragma unroll
        for (int c = 0; c < 12; ++c) cc[c] = 0.0f;

        #pragma unroll
        for (int dz = 0; dz < 2; ++dz)
        #pragma unroll
        for (int dy = 0; dy < 2; ++dy)
        #pragma unroll
        for (int dx = 0; dx < 2; ++dx) {
            float w = wxa[dx] * wya[dy] * wza[dz];
            if (!(vxa[dx] && vya[dy] && vza[dz])) w = 0.0f;
            const int gi = (cza[dz]*100 + cya[dy])*100 + cxa[dx];
            den += w * g_gd[gi];
            #pragma unroll
            for (int c = 0; c < 12; ++c) cc[c] += w * g_gc[c*1000000 + gi];
        }

        const float interval = sqrtf(d0*d0 + d1*d1 + d2*d2);
        const float e = expf(den + ACT_SHIFT_F);
        const float alpha = -expm1f(-interval * log1pf(e));  // 1-(1+e)^(-t), accurate f32
        out_alpha[ray*128 + p] = alpha;

        #pragma unroll
        for (int c = 0; c < 12; ++c) STA(p, c, cc[c]);
    } else {
        const int p = tid - 128;
        STA(p, 12, d0); STA(p, 13, d1); STA(p, 14, d2);
        #pragma unroll
        for (int i = 0; i < 3; ++i) {
            const float di = (i == 0) ? d0 : ((i == 1) ? d1 : d2);
            #pragma unroll
            for (int j = 0; j < 4; ++j) {
                const float a = di * (float)(1 << j);
                STA(p, 15 + i*4 + j, sinf(a));
                STA(p, 27 + i*4 + j, cosf(a));
            }
        }
        #pragma unroll
        for (int c = 39; c < 64; ++c) STA(p, c, 0.0f);
    }
    __syncthreads();

    // ---- GEMM1: h1[128x128] = relu(feat[128x64] @ w1[64x128] + b1) ----
    const int lane = tid & 63;
    const int wid  = tid >> 6;
    const int lr   = lane & 15;   // row (A) / col (B,D)
    const int lk   = lane >> 4;   // k-group / D row-group
    const int r0   = wid * 32;

    f32x4 acc1[2][8];
    #pragma unroll
    for (int rt = 0; rt < 2; ++rt)
        #pragma unroll
        for (int ct = 0; ct < 8; ++ct) acc1[rt][ct] = (f32x4){0.f,0.f,0.f,0.f};

    bf16x8 a1[2][2];
    #pragma unroll
    for (int rt = 0; rt < 2; ++rt)
        #pragma unroll
        for (int ks = 0; ks < 2; ++ks) {
            const int row = r0 + rt*16 + lr;
            int a = SA_OFF + row*128 + ks*64 + lk*16; a ^= ((row & 7) << 4);
            a1[rt][ks] = *reinterpret_cast<const bf16x8*>(smem + a);
        }
    #pragma unroll
    for (int ct = 0; ct < 8; ++ct) {
        const int n = ct*16 + lr;
        int a0 = SW1_OFF + n*128 +  0 + lk*16; a0 ^= ((n & 7) << 4);
        int a1b= SW1_OFF + n*128 + 64 + lk*16; a1b^= ((n & 7) << 4);
        const bf16x8 b0 = *reinterpret_cast<const bf16x8*>(smem + a0);
        const bf16x8 b1 = *reinterpret_cast<const bf16x8*>(smem + a1b);
        #pragma unroll
        for (int rt = 0; rt < 2; ++rt) {
            acc1[rt][ct] = __builtin_amdgcn_mfma_f32_16x16x32_bf16(a1[rt][0], b0, acc1[rt][ct], 0, 0, 0);
            acc1[rt][ct] = __builtin_amdgcn_mfma_f32_16x16x32_bf16(a1[rt][1], b1, acc1[rt][ct], 0, 0, 0);
        }
    }
    // epilogue: +b1, relu, bf16 -> h1 (swizzled)
    {
        float bias1[8];
        #pragma unroll
        for (int ct = 0; ct < 8; ++ct) bias1[ct] = g_b1[ct*16 + lr];
        #pragma unroll
        for (int rt = 0; rt < 2; ++rt)
            #pragma unroll
            for (int ct = 0; ct < 8; ++ct)
                #pragma unroll
                for (int reg = 0; reg < 4; ++reg) {
                    const int row = r0 + rt*16 + lk*4 + reg;
                    const float v = fmaxf(acc1[rt][ct][reg] + bias1[ct], 0.0f);
                    int a = H1_OFF + row*256 + (ct*16 + lr)*2; a ^= ((row & 7) << 4);
                    *reinterpret_cast<__bf16*>(smem + a) = (__bf16)v;
                }
    }
    __syncthreads();

    // ---- stage w2 -> sW2t[n][k] bf16 swizzled (overwrites sA/sW1t) ----
    for (int idx = tid; idx < 128*128; idx += 256) {
        const int kk = idx >> 7, n = idx & 127;
        const float v = g_w2[idx];                  // coalesced: idx = kk*128+n
        int a = SW2_OFF + n*256 + kk*2; a ^= ((n & 7) << 4);
        *reinterpret_cast<__bf16*>(smem + a) = (__bf16)v;
    }
    __syncthreads();

    // ---- GEMM2: h2 = relu(h1 @ w2 + b2) kept in accumulators ----
    f32x4 acc2[2][8];
    #pragma unroll
    for (int rt = 0; rt < 2; ++rt)
        #pragma unroll
        for (int ct = 0; ct < 8; ++ct) acc2[rt][ct] = (f32x4){0.f,0.f,0.f,0.f};

    bf16x8 a2[2][4];
    #pragma unroll
    for (int rt = 0; rt < 2; ++rt)
        #pragma unroll
        for (int ks = 0; ks < 4; ++ks) {
            const int row = r0 + rt*16 + lr;
            int a = H1_OFF + row*256 + ks*64 + lk*16; a ^= ((row & 7) << 4);
            a2[rt][ks] = *reinterpret_cast<const bf16x8*>(smem + a);
        }
    #pragma unroll
    for (int ct = 0; ct < 8; ++ct) {
        const int n = ct*16 + lr;
        bf16x8 bw[4];
        #pragma unroll
        for (int ks = 0; ks < 4; ++ks) {
            int a = SW2_OFF + n*256 + ks*64 + lk*16; a ^= ((n & 7) << 4);
            bw[ks] = *reinterpret_cast<const bf16x8*>(smem + a);
        }
        #pragma unroll
        for (int rt = 0; rt < 2; ++rt)
            #pragma unroll
            for (int ks = 0; ks < 4; ++ks)
                acc2[rt][ct] = __builtin_amdgcn_mfma_f32_16x16x32_bf16(a2[rt][ks], bw[ks], acc2[rt][ct], 0, 0, 0);
    }

    // ---- phase D: rgb = sigmoid(relu(h2) @ w3 + b3), from accumulators ----
    float b2v[8], w30[8], w31[8], w32[8];
    #pragma unroll
    for (int ct = 0; ct < 8; ++ct) {
        const int n = ct*16 + lr;
        b2v[ct] = g_b2[n];
        w30[ct] = g_w3[n*3 + 0];
        w31[ct] = g_w3[n*3 + 1];
        w32[ct] = g_w3[n*3 + 2];
    }
    const float bb0 = g_b3[0], bb1 = g_b3[1], bb2 = g_b3[2];

    #pragma unroll
    for (int rt = 0; rt < 2; ++rt)
        #pragma unroll
        for (int reg = 0; reg < 4; ++reg) {
            float s0 = 0.f, s1 = 0.f, s2 = 0.f;
            #pragma unroll
            for (int ct = 0; ct < 8; ++ct) {
                const float v = fmaxf(acc2[rt][ct][reg] + b2v[ct], 0.0f);
                s0 = fmaf(v, w30[ct], s0);
                s1 = fmaf(v, w31[ct], s1);
                s2 = fmaf(v, w32[ct], s2);
            }
            #pragma unroll
            for (int off = 1; off < 16; off <<= 1) {
                s0 += __shfl_xor(s0, off);
                s1 += __shfl_xor(s1, off);
                s2 += __shfl_xor(s2, off);
            }
            if (lr == 0) {
                const int row = r0 + rt*16 + lk*4 + reg;
                const int pt  = ray*128 + row;
                out_rgb[pt*3 + 0] = 1.0f / (1.0f + expf(-(s0 + bb0)));
                out_rgb[pt*3 + 1] = 1.0f / (1.0f + expf(-(s1 + bb1)));
                out_rgb[pt*3 + 2] = 1.0f / (1.0f + expf(-(s2 + bb2)));
            }
        }
}

extern "C" void kernel_launch(void* const* d_in, const int* in_sizes, int n_in,
                              void* d_out, int out_size, void* d_ws, size_t ws_size,
                              hipStream_t stream)
{
    const float* g_org = (const float*)d_in[0];
    const float* g_dir = (const float*)d_in[1];
    const float* g_len = (const float*)d_in[2];
    const float* g_gd  = (const float*)d_in[3];
    const float* g_gc  = (const float*)d_in[4];
    const float* g_w1  = (const float*)d_in[5];
    const float* g_b1  = (const float*)d_in[6];
    const float* g_w2  = (const float*)d_in[7];
    const float* g_b2  = (const float*)d_in[8];
    const float* g_w3  = (const float*)d_in[9];
    const float* g_b3  = (const float*)d_in[10];
    float* out = (float*)d_out;

    dvgo_fused<<<4096, 256, 0, stream>>>(g_org, g_dir, g_len, g_gd, g_gc,
                                         g_w1, g_b1, g_w2, g_b2, g_w3, g_b3,
                                         out, out + 4096*128);
}

// Round 2
// 165.494 us; speedup vs baseline: 1.2976x; 1.2976x over previous
//
#include <hip/hip_runtime.h>
#include <hip/hip_bf16.h>
#include <math.h>

// DirectVoxGO fused forward, v2.
// Prep kernel: pre-swizzle w1/w2 into bf16 MFMA-fragment layout in ws (48 KB).
// Main kernel: 1 block = 1 ray, 256 threads (4 waves), LDS 48 KB (3 blocks/CU).
//   gather (all 256 threads, 2 per point) -> alpha + feat tile (bf16, swizzled LDS)
//   GEMM1 swapped (D=[n][pt]) -> h1[pt][n] LDS via b64 stores
//   GEMM2 (waves = 64pt x 64N) with w2 fragments streamed global->reg (L2-hit)
//   epilogue N=3 on VALU, shfl reduce + LDS partial, sigmoid -> rgb

typedef __bf16 bf16x4 __attribute__((ext_vector_type(4)));
typedef __bf16 bf16x8 __attribute__((ext_vector_type(8)));
typedef float  f32x4  __attribute__((ext_vector_type(4)));

#define ACT_SHIFT_F (-13.815509557964774f)

#define FEAT_OFF 0        // [128][64] bf16 = 16 KB, swizzled ^((p&7)<<4); later prgb[2][128][3] f32
#define H1_OFF   16384    // [128][128] bf16 = 32 KB, swizzled; pre-GEMM1 holds pcc[128][13] f32

// ---------------- prep: weights -> fragment-linear bf16 in ws ----------------
// ws bf16 elems [0,8192)  : w1 A-frags  [ct=8][ks=2][lane=64][j=8], k>=39 zeroed
// ws bf16 elems [8192,24576): w2 B-frags [ct=8][ks=4][lane=64][j=8]
__global__ void dvgo_prep(const float* __restrict__ g_w1,
                          const float* __restrict__ g_w2,
                          __bf16* __restrict__ wsb)
{
    const int idx = blockIdx.x * 256 + threadIdx.x;
    if (idx < 8192) {
        const int j = idx & 7, lane = (idx >> 3) & 63, ks = (idx >> 9) & 1, ct = idx >> 10;
        const int n = ct * 16 + (lane & 15);
        const int k = ks * 32 + ((lane >> 4) & 3) * 8 + j;
        const float v = (k < 39) ? g_w1[k * 128 + n] : 0.0f;
        wsb[idx] = (__bf16)v;
    } else if (idx < 24576) {
        const int i2 = idx - 8192;
        const int j = i2 & 7, lane = (i2 >> 3) & 63, ks = (i2 >> 9) & 3, ct = i2 >> 11;
        const int n = ct * 16 + (lane & 15);
        const int k = ks * 32 + ((lane >> 4) & 3) * 8 + j;
        wsb[idx] = (__bf16)g_w2[k * 128 + n];
    }
}

// ---------------- main ----------------
__global__ __launch_bounds__(256, 3)
void dvgo_fused(const float* __restrict__ g_org, const float* __restrict__ g_dir,
                const float* __restrict__ g_len, const float* __restrict__ g_gd,
                const float* __restrict__ g_gc, const float* __restrict__ g_b1,
                const float* __restrict__ g_b2, const float* __restrict__ g_w3,
                const float* __restrict__ g_b3, const bf16x8* __restrict__ wf,
                float* __restrict__ out_alpha, float* __restrict__ out_rgb)
{
    __shared__ __align__(16) char smem[49152];
    float* smf = (float*)smem;
    const int tid = threadIdx.x;
    const int ray = blockIdx.x;

    const float d0 = g_dir[ray*3+0], d1 = g_dir[ray*3+1], d2 = g_dir[ray*3+2];

    // ================= gather: 2 threads per point, split by dz =================
    {
        const float o0 = g_org[ray*3+0], o1 = g_org[ray*3+1], o2 = g_org[ray*3+2];
        const int p = tid & 127;
        const int dzv = tid >> 7;
        const float len = g_len[ray*128 + p];
        const float px = (o0 + d0*len + 1.0f) * 49.5f;
        const float py = (o1 + d1*len + 1.0f) * 49.5f;
        const float pz = (o2 + d2*len + 1.0f) * 49.5f;
        const float fx = floorf(px), fy = floorf(py), fz = floorf(pz);
        const int ix = (int)fx, iy = (int)fy, iz0 = (int)fz;
        const float qx = px - fx, qy = py - fy, qz = pz - fz;
        const float wxa[2] = {1.0f - qx, qx};
        const float wya[2] = {1.0f - qy, qy};
        const int  cxa[2] = {min(max(ix,0),99),   min(max(ix+1,0),99)};
        const int  cya[2] = {min(max(iy,0),99),   min(max(iy+1,0),99)};
        const bool vxa[2] = {(unsigned)ix < 100u, (unsigned)(ix+1) < 100u};
        const bool vya[2] = {(unsigned)iy < 100u, (unsigned)(iy+1) < 100u};
        const int  iz = iz0 + dzv;
        const float wz = dzv ? qz : (1.0f - qz);
        const int  cz = min(max(iz,0),99);
        const bool vz = (unsigned)iz < 100u;

        float den = 0.0f;
        float cc[12];
        #pragma unroll
        for (int c = 0; c < 12; ++c) cc[c] = 0.0f;

        #pragma unroll
        for (int dy = 0; dy < 2; ++dy)
        #pragma unroll
        for (int dx = 0; dx < 2; ++dx) {
            float w = wxa[dx] * wya[dy] * wz;
            if (!(vxa[dx] && vya[dy] && vz)) w = 0.0f;
            const int gi = (cz*100 + cya[dy])*100 + cxa[dx];
            den += w * g_gd[gi];
            #pragma unroll
            for (int c = 0; c < 12; ++c) cc[c] += w * g_gc[c*1000000 + gi];
        }

        if (dzv) {   // write f32 partials into (future) h1 region
            #pragma unroll
            for (int c = 0; c < 12; ++c) smf[H1_OFF/4 + p*13 + c] = cc[c];
            smf[H1_OFF/4 + p*13 + 12] = den;
        }
        __syncthreads();   // B1: partials visible

        if (!dzv) {
            #pragma unroll
            for (int c = 0; c < 12; ++c) cc[c] += smf[H1_OFF/4 + p*13 + c];
            den += smf[H1_OFF/4 + p*13 + 12];

            const float interval = sqrtf(d0*d0 + d1*d1 + d2*d2);
            const float e = expf(den + ACT_SHIFT_F);
            out_alpha[ray*128 + p] = -expm1f(-interval * log1pf(e));

            // feat cols 0..11 (b128 + b64, swizzled)
            bf16x8 f0; bf16x4 f1;
            #pragma unroll
            for (int c = 0; c < 8; ++c) f0[c] = (__bf16)cc[c];
            #pragma unroll
            for (int c = 0; c < 4; ++c) f1[c] = (__bf16)cc[8+c];
            const int swz = (p & 7) << 4;
            *reinterpret_cast<bf16x8*>(smem + ((FEAT_OFF + p*128 +  0) ^ swz)) = f0;
            *reinterpret_cast<bf16x4*>(smem + ((FEAT_OFF + p*128 + 16) ^ swz)) = f1;
        } else {
            // feat cols 12..63: [d0,d1,d2, sin(12), cos(12), zeros...]
            float vals[52];
            vals[0] = d0; vals[1] = d1; vals[2] = d2;
            #pragma unroll
            for (int i = 0; i < 3; ++i) {
                const float di = (i == 0) ? d0 : ((i == 1) ? d1 : d2);
                #pragma unroll
                for (int j = 0; j < 4; ++j) {
                    const float a = di * (float)(1 << j);
                    vals[3  + i*4 + j] = sinf(a);
                    vals[15 + i*4 + j] = cosf(a);
                }
            }
            #pragma unroll
            for (int c = 27; c < 52; ++c) vals[c] = 0.0f;
            const int swz = (p & 7) << 4;
            #pragma unroll
            for (int i = 0; i < 13; ++i) {
                bf16x4 v4;
                #pragma unroll
                for (int r = 0; r < 4; ++r) v4[r] = (__bf16)vals[i*4 + r];
                *reinterpret_cast<bf16x4*>(smem + ((FEAT_OFF + p*128 + 24 + i*8) ^ swz)) = v4;
            }
        }
    }
    __syncthreads();   // B2: feat tile ready (h1 region partials dead)

    const int lane = tid & 63;
    const int wid  = tid >> 6;
    const int lr   = lane & 15;
    const int lk   = lane >> 4;

    // ============ GEMM1 (swapped): D[n][pt], wave = 32 pts x all 128 n ============
    {
        bf16x8 bf[2][2];
        #pragma unroll
        for (int rt = 0; rt < 2; ++rt)
            #pragma unroll
            for (int ks = 0; ks < 2; ++ks) {
                const int pt = wid*32 + rt*16 + lr;
                int a = FEAT_OFF + pt*128 + ks*64 + lk*16; a ^= (pt & 7) << 4;
                bf[rt][ks] = *reinterpret_cast<const bf16x8*>(smem + a);
            }
        f32x4 acc1[2][8];
        #pragma unroll
        for (int rt = 0; rt < 2; ++rt)
            #pragma unroll
            for (int ct = 0; ct < 8; ++ct) acc1[rt][ct] = (f32x4){0.f,0.f,0.f,0.f};
        #pragma unroll
        for (int ct = 0; ct < 8; ++ct) {
            const bf16x8 aw0 = wf[(ct*2 + 0)*64 + lane];
            const bf16x8 aw1 = wf[(ct*2 + 1)*64 + lane];
            #pragma unroll
            for (int rt = 0; rt < 2; ++rt) {
                acc1[rt][ct] = __builtin_amdgcn_mfma_f32_16x16x32_bf16(aw0, bf[rt][0], acc1[rt][ct], 0, 0, 0);
                acc1[rt][ct] = __builtin_amdgcn_mfma_f32_16x16x32_bf16(aw1, bf[rt][1], acc1[rt][ct], 0, 0, 0);
            }
        }
        // epilogue: +b1, relu -> h1[pt][n] (b64 contiguous in n, swizzled)
        #pragma unroll
        for (int ct = 0; ct < 8; ++ct) {
            const f32x4 b1v = *reinterpret_cast<const f32x4*>(g_b1 + ct*16 + lk*4);
            #pragma unroll
            for (int rt = 0; rt < 2; ++rt) {
                const int pt = wid*32 + rt*16 + lr;
                bf16x4 hv;
                #pragma unroll
                for (int r = 0; r < 4; ++r)
                    hv[r] = (__bf16)fmaxf(acc1[rt][ct][r] + b1v[r], 0.0f);
                int a = H1_OFF + pt*256 + ct*32 + lk*8; a ^= (pt & 7) << 4;
                *reinterpret_cast<bf16x4*>(smem + a) = hv;
            }
        }
    }
    __syncthreads();   // B3: h1 ready (feat region dead -> prgb)

    // ============ GEMM2: wave = 64 pts x 64 n2; w2 frags streamed from L2 ============
    const int wr = wid >> 1, wc = wid & 1;
    f32x4 acc2[4][4];
    #pragma unroll
    for (int rt = 0; rt < 4; ++rt)
        #pragma unroll
        for (int ct = 0; ct < 4; ++ct) acc2[rt][ct] = (f32x4){0.f,0.f,0.f,0.f};

    #pragma unroll
    for (int ks = 0; ks < 4; ++ks) {
        bf16x8 a2[4];
        #pragma unroll
        for (int rt = 0; rt < 4; ++rt) {
            const int pt = wr*64 + rt*16 + lr;
            int a = H1_OFF + pt*256 + ks*64 + lk*16; a ^= (pt & 7) << 4;
            a2[rt] = *reinterpret_cast<const bf16x8*>(smem + a);
        }
        #pragma unroll
        for (int ct = 0; ct < 4; ++ct) {
            const int ctg = wc*4 + ct;
            const bf16x8 b2f = wf[1024 + (ctg*4 + ks)*64 + lane];
            #pragma unroll
            for (int rt = 0; rt < 4; ++rt)
                acc2[rt][ct] = __builtin_amdgcn_mfma_f32_16x16x32_bf16(a2[rt], b2f, acc2[rt][ct], 0, 0, 0);
        }
    }

    // ============ epilogue: partial rgb over this wave's 64-n2 half ============
    {
        float b2v[4], w30[4], w31[4], w32[4];
        #pragma unroll
        for (int ct = 0; ct < 4; ++ct) {
            const int n2 = wc*64 + ct*16 + lr;
            b2v[ct] = g_b2[n2];
            w30[ct] = g_w3[n2*3 + 0];
            w31[ct] = g_w3[n2*3 + 1];
            w32[ct] = g_w3[n2*3 + 2];
        }
        #pragma unroll
        for (int rt = 0; rt < 4; ++rt)
            #pragma unroll
            for (int r = 0; r < 4; ++r) {
                float s0 = 0.f, s1 = 0.f, s2 = 0.f;
                #pragma unroll
                for (int ct = 0; ct < 4; ++ct) {
                    const float v = fmaxf(acc2[rt][ct][r] + b2v[ct], 0.0f);
                    s0 = fmaf(v, w30[ct], s0);
                    s1 = fmaf(v, w31[ct], s1);
                    s2 = fmaf(v, w32[ct], s2);
                }
                #pragma unroll
                for (int off = 1; off < 16; off <<= 1) {
                    s0 += __shfl_xor(s0, off);
                    s1 += __shfl_xor(s1, off);
                    s2 += __shfl_xor(s2, off);
                }
                if (lr == 0) {
                    const int pt = wr*64 + rt*16 + lk*4 + r;
                    const int base = (wc*128 + pt)*3;
                    smf[base + 0] = s0;
                    smf[base + 1] = s1;
                    smf[base + 2] = s2;
                }
            }
    }
    __syncthreads();   // B4: prgb ready

    if (tid < 128) {
        const int p = tid;
        const float bb0 = g_b3[0], bb1 = g_b3[1], bb2 = g_b3[2];
        const float s0 = smf[p*3 + 0] + smf[(128 + p)*3 + 0] + bb0;
        const float s1 = smf[p*3 + 1] + smf[(128 + p)*3 + 1] + bb1;
        const float s2 = smf[p*3 + 2] + smf[(128 + p)*3 + 2] + bb2;
        const int pt = ray*128 + p;
        out_rgb[pt*3 + 0] = 1.0f / (1.0f + expf(-s0));
        out_rgb[pt*3 + 1] = 1.0f / (1.0f + expf(-s1));
        out_rgb[pt*3 + 2] = 1.0f / (1.0f + expf(-s2));
    }
}

extern "C" void kernel_launch(void* const* d_in, const int* in_sizes, int n_in,
                              void* d_out, int out_size, void* d_ws, size_t ws_size,
                              hipStream_t stream)
{
    const float* g_org = (const float*)d_in[0];
    const float* g_dir = (const float*)d_in[1];
    const float* g_len = (const float*)d_in[2];
    const float* g_gd  = (const float*)d_in[3];
    const float* g_gc  = (const float*)d_in[4];
    const float* g_w1  = (const float*)d_in[5];
    const float* g_b1  = (const float*)d_in[6];
    const float* g_w2  = (const float*)d_in[7];
    const float* g_b2  = (const float*)d_in[8];
    const float* g_w3  = (const float*)d_in[9];
    const float* g_b3  = (const float*)d_in[10];
    float* out = (float*)d_out;

    dvgo_prep<<<96, 256, 0, stream>>>(g_w1, g_w2, (__bf16*)d_ws);
    dvgo_fused<<<4096, 256, 0, stream>>>(g_org, g_dir, g_len, g_gd, g_gc,
                                         g_b1, g_b2, g_w3, g_b3,
                                         (const bf16x8*)d_ws,
                                         out, out + 4096*128);
}

// Round 3
// 141.923 us; speedup vs baseline: 1.5131x; 1.1661x over previous
//
#include <hip/hip_runtime.h>
#include <hip/hip_bf16.h>
#include <math.h>

// DirectVoxGO fused forward, v3.
// Prep A: w1/w2 -> bf16 MFMA-fragment layout in ws[0, 48K).
// Prep B: density+color grids -> packed AoS bf16 [voxel][16ch] (32 B/voxel) in
//         ws[48K, 48K+32MB) -- one corner gather = 2 x b128 instead of 13 scalars.
// Main: 1 block = 1 ray, 256 threads, LDS 32 KB (5 blocks/CU target).
//   gather (2 threads/point, dz split) -> alpha + feat tile (bf16, swizzled)
//   GEMM1 swapped (D=[n][pt]) -> h1[pt][n] LDS (h1 overwrites feat after B2b)
//   GEMM2 (waves = 64pt x 64N), w2 frags global->reg (L2-hit)
//   epilogue N=3 on VALU, shfl reduce + LDS partial (reuses h1), sigmoid -> rgb

typedef __bf16 bf16x4 __attribute__((ext_vector_type(4)));
typedef __bf16 bf16x8 __attribute__((ext_vector_type(8)));
typedef float  f32x4  __attribute__((ext_vector_type(4)));

#define ACT_SHIFT_F (-13.815509557964774f)

#define FEAT_OFF 0        // [128][64] bf16 = 16 KB, swizzled ^((p&7)<<4)
#define PCC_OFF  16384    // f32 partials [128][13] = 6.5 KB (gather phase only)
#define H1_OFF   0        // [128][128] bf16 = 32 KB (after feat consumed)
#define PRGB_OFF 0        // f32 [2][128][3] = 3 KB (after h1 consumed)

// ---------------- prep A: weights -> fragment-linear bf16 ----------------
// ws bf16 [0,8192): w1 A-frags [ct=8][ks=2][lane=64][j=8], k>=39 zeroed
// ws bf16 [8192,24576): w2 B-frags [ct=8][ks=4][lane=64][j=8]
__global__ void dvgo_prep_w(const float* __restrict__ g_w1,
                            const float* __restrict__ g_w2,
                            __bf16* __restrict__ wsb)
{
    const int idx = blockIdx.x * 256 + threadIdx.x;
    if (idx < 8192) {
        const int j = idx & 7, lane = (idx >> 3) & 63, ks = (idx >> 9) & 1, ct = idx >> 10;
        const int n = ct * 16 + (lane & 15);
        const int k = ks * 32 + ((lane >> 4) & 3) * 8 + j;
        wsb[idx] = (__bf16)((k < 39) ? g_w1[k * 128 + n] : 0.0f);
    } else if (idx < 24576) {
        const int i2 = idx - 8192;
        const int j = i2 & 7, lane = (i2 >> 3) & 63, ks = (i2 >> 9) & 3, ct = i2 >> 11;
        const int n = ct * 16 + (lane & 15);
        const int k = ks * 32 + ((lane >> 4) & 3) * 8 + j;
        wsb[idx] = (__bf16)g_w2[k * 128 + n];
    }
}

// ---------------- prep B: grids -> packed AoS bf16 [gi][16] ----------------
__global__ __launch_bounds__(256) void dvgo_prep_grid(const float* __restrict__ g_gd,
                                                      const float* __restrict__ g_gc,
                                                      bf16x8* __restrict__ pack)
{
    const int gi = blockIdx.x * 256 + threadIdx.x;
    if (gi >= 1000000) return;
    bf16x8 v0, v1;
    #pragma unroll
    for (int c = 0; c < 8; ++c) v0[c] = (__bf16)g_gc[c * 1000000 + gi];
    #pragma unroll
    for (int c = 0; c < 4; ++c) v1[c] = (__bf16)g_gc[(8 + c) * 1000000 + gi];
    v1[4] = (__bf16)g_gd[gi];
    v1[5] = (__bf16)0.0f; v1[6] = (__bf16)0.0f; v1[7] = (__bf16)0.0f;
    pack[gi * 2 + 0] = v0;
    pack[gi * 2 + 1] = v1;
}

// ---------------- main ----------------
template <bool PACKED>
__global__ __launch_bounds__(256, 5)
void dvgo_main(const float* __restrict__ g_org, const float* __restrict__ g_dir,
               const float* __restrict__ g_len, const float* __restrict__ g_gd,
               const float* __restrict__ g_gc, const float* __restrict__ g_b1,
               const float* __restrict__ g_b2, const float* __restrict__ g_w3,
               const float* __restrict__ g_b3, const bf16x8* __restrict__ wf,
               const bf16x8* __restrict__ g_pack,
               float* __restrict__ out_alpha, float* __restrict__ out_rgb)
{
    __shared__ __align__(16) char smem[32768];
    float* smf = (float*)smem;
    const int tid = threadIdx.x;
    const int ray = blockIdx.x;

    const float d0 = g_dir[ray*3+0], d1 = g_dir[ray*3+1], d2 = g_dir[ray*3+2];

    // ================= gather: 2 threads per point, split by dz =================
    {
        const float o0 = g_org[ray*3+0], o1 = g_org[ray*3+1], o2 = g_org[ray*3+2];
        const int p = tid & 127;
        const int dzv = tid >> 7;
        const float len = g_len[ray*128 + p];
        const float px = (o0 + d0*len + 1.0f) * 49.5f;
        const float py = (o1 + d1*len + 1.0f) * 49.5f;
        const float pz = (o2 + d2*len + 1.0f) * 49.5f;
        const float fx = floorf(px), fy = floorf(py), fz = floorf(pz);
        const int ix = (int)fx, iy = (int)fy, iz0 = (int)fz;
        const float qx = px - fx, qy = py - fy, qz = pz - fz;
        const float wxa[2] = {1.0f - qx, qx};
        const float wya[2] = {1.0f - qy, qy};
        const int  cxa[2] = {min(max(ix,0),99),   min(max(ix+1,0),99)};
        const int  cya[2] = {min(max(iy,0),99),   min(max(iy+1,0),99)};
        const bool vxa[2] = {(unsigned)ix < 100u, (unsigned)(ix+1) < 100u};
        const bool vya[2] = {(unsigned)iy < 100u, (unsigned)(iy+1) < 100u};
        const int  iz = iz0 + dzv;
        const float wz = dzv ? qz : (1.0f - qz);
        const int  cz = min(max(iz,0),99);
        const bool vz = (unsigned)iz < 100u;

        float den = 0.0f;
        float cc[12];
        #pragma unroll
        for (int c = 0; c < 12; ++c) cc[c] = 0.0f;

        if (PACKED) {
            #pragma unroll
            for (int dy = 0; dy < 2; ++dy)
            #pragma unroll
            for (int dx = 0; dx < 2; ++dx) {
                float w = wxa[dx] * wya[dy] * wz;
                if (!(vxa[dx] && vya[dy] && vz)) w = 0.0f;
                const int gi = (cz*100 + cya[dy])*100 + cxa[dx];
                const bf16x8 v0 = g_pack[gi*2 + 0];
                const bf16x8 v1 = g_pack[gi*2 + 1];
                #pragma unroll
                for (int c = 0; c < 8; ++c) cc[c]     += w * (float)v0[c];
                #pragma unroll
                for (int c = 0; c < 4; ++c) cc[8 + c] += w * (float)v1[c];
                den += w * (float)v1[4];
            }
        } else {
            #pragma unroll
            for (int dy = 0; dy < 2; ++dy)
            #pragma unroll
            for (int dx = 0; dx < 2; ++dx) {
                float w = wxa[dx] * wya[dy] * wz;
                if (!(vxa[dx] && vya[dy] && vz)) w = 0.0f;
                const int gi = (cz*100 + cya[dy])*100 + cxa[dx];
                den += w * g_gd[gi];
                #pragma unroll
                for (int c = 0; c < 12; ++c) cc[c] += w * g_gc[c*1000000 + gi];
            }
        }

        if (dzv) {   // write f32 partials
            #pragma unroll
            for (int c = 0; c < 12; ++c) smf[PCC_OFF/4 + p*13 + c] = cc[c];
            smf[PCC_OFF/4 + p*13 + 12] = den;
        }
        __syncthreads();   // B1: partials visible

        if (!dzv) {
            #pragma unroll
            for (int c = 0; c < 12; ++c) cc[c] += smf[PCC_OFF/4 + p*13 + c];
            den += smf[PCC_OFF/4 + p*13 + 12];

            const float interval = sqrtf(d0*d0 + d1*d1 + d2*d2);
            const float e = expf(den + ACT_SHIFT_F);
            out_alpha[ray*128 + p] = -expm1f(-interval * log1pf(e));

            bf16x8 f0; bf16x4 f1;
            #pragma unroll
            for (int c = 0; c < 8; ++c) f0[c] = (__bf16)cc[c];
            #pragma unroll
            for (int c = 0; c < 4; ++c) f1[c] = (__bf16)cc[8+c];
            const int swz = (p & 7) << 4;
            *reinterpret_cast<bf16x8*>(smem + ((FEAT_OFF + p*128 +  0) ^ swz)) = f0;
            *reinterpret_cast<bf16x4*>(smem + ((FEAT_OFF + p*128 + 16) ^ swz)) = f1;
        } else {
            // feat cols 12..63: [d0,d1,d2, sin(12), cos(12), zeros...]
            float vals[52];
            vals[0] = d0; vals[1] = d1; vals[2] = d2;
            #pragma unroll
            for (int i = 0; i < 3; ++i) {
                const float di = (i == 0) ? d0 : ((i == 1) ? d1 : d2);
                #pragma unroll
                for (int j = 0; j < 4; ++j) {
                    const float a = di * (float)(1 << j);
                    vals[3  + i*4 + j] = sinf(a);
                    vals[15 + i*4 + j] = cosf(a);
                }
            }
            #pragma unroll
            for (int c = 27; c < 52; ++c) vals[c] = 0.0f;
            const int swz = (p & 7) << 4;
            #pragma unroll
            for (int i = 0; i < 13; ++i) {
                bf16x4 v4;
                #pragma unroll
                for (int r = 0; r < 4; ++r) v4[r] = (__bf16)vals[i*4 + r];
                *reinterpret_cast<bf16x4*>(smem + ((FEAT_OFF + p*128 + 24 + i*8) ^ swz)) = v4;
            }
        }
    }
    __syncthreads();   // B2: feat tile ready

    const int lane = tid & 63;
    const int wid  = tid >> 6;
    const int lr   = lane & 15;
    const int lk   = lane >> 4;

    // ============ GEMM1 (swapped): D[n][pt], wave = 32 pts x all 128 n ============
    {
        bf16x8 bf[2][2];
        #pragma unroll
        for (int rt = 0; rt < 2; ++rt)
            #pragma unroll
            for (int ks = 0; ks < 2; ++ks) {
                const int pt = wid*32 + rt*16 + lr;
                int a = FEAT_OFF + pt*128 + ks*64 + lk*16; a ^= (pt & 7) << 4;
                bf[rt][ks] = *reinterpret_cast<const bf16x8*>(smem + a);
            }
        __syncthreads();   // B2b: all feat reads in regs; h1 may overwrite

        f32x4 acc1[2][8];
        #pragma unroll
        for (int rt = 0; rt < 2; ++rt)
            #pragma unroll
            for (int ct = 0; ct < 8; ++ct) acc1[rt][ct] = (f32x4){0.f,0.f,0.f,0.f};
        #pragma unroll
        for (int ct = 0; ct < 8; ++ct) {
            const bf16x8 aw0 = wf[(ct*2 + 0)*64 + lane];
            const bf16x8 aw1 = wf[(ct*2 + 1)*64 + lane];
            #pragma unroll
            for (int rt = 0; rt < 2; ++rt) {
                acc1[rt][ct] = __builtin_amdgcn_mfma_f32_16x16x32_bf16(aw0, bf[rt][0], acc1[rt][ct], 0, 0, 0);
                acc1[rt][ct] = __builtin_amdgcn_mfma_f32_16x16x32_bf16(aw1, bf[rt][1], acc1[rt][ct], 0, 0, 0);
            }
        }
        // epilogue: +b1, relu -> h1[pt][n] (swizzled)
        #pragma unroll
        for (int ct = 0; ct < 8; ++ct) {
            const f32x4 b1v = *reinterpret_cast<const f32x4*>(g_b1 + ct*16 + lk*4);
            #pragma unroll
            for (int rt = 0; rt < 2; ++rt) {
                const int pt = wid*32 + rt*16 + lr;
                bf16x4 hv;
                #pragma unroll
                for (int r = 0; r < 4; ++r)
                    hv[r] = (__bf16)fmaxf(acc1[rt][ct][r] + b1v[r], 0.0f);
                int a = H1_OFF + pt*256 + ct*32 + lk*8; a ^= (pt & 7) << 4;
                *reinterpret_cast<bf16x4*>(smem + a) = hv;
            }
        }
    }
    __syncthreads();   // B3: h1 ready

    // ============ GEMM2: wave = 64 pts x 64 n2; w2 frags streamed from L2 ============
    const int wr = wid >> 1, wc = wid & 1;
    f32x4 acc2[4][4];
    #pragma unroll
    for (int rt = 0; rt < 4; ++rt)
        #pragma unroll
        for (int ct = 0; ct < 4; ++ct) acc2[rt][ct] = (f32x4){0.f,0.f,0.f,0.f};

    #pragma unroll
    for (int ks = 0; ks < 4; ++ks) {
        bf16x8 a2[4];
        #pragma unroll
        for (int rt = 0; rt < 4; ++rt) {
            const int pt = wr*64 + rt*16 + lr;
            int a = H1_OFF + pt*256 + ks*64 + lk*16; a ^= (pt & 7) << 4;
            a2[rt] = *reinterpret_cast<const bf16x8*>(smem + a);
        }
        #pragma unroll
        for (int ct = 0; ct < 4; ++ct) {
            const int ctg = wc*4 + ct;
            const bf16x8 b2f = wf[1024 + (ctg*4 + ks)*64 + lane];
            #pragma unroll
            for (int rt = 0; rt < 4; ++rt)
                acc2[rt][ct] = __builtin_amdgcn_mfma_f32_16x16x32_bf16(a2[rt], b2f, acc2[rt][ct], 0, 0, 0);
        }
    }
    __syncthreads();   // B3b: all h1 reads done; prgb may overwrite

    // ============ epilogue: partial rgb over this wave's 64-n2 half ============
    {
        float b2v[4], w30[4], w31[4], w32[4];
        #pragma unroll
        for (int ct = 0; ct < 4; ++ct) {
            const int n2 = wc*64 + ct*16 + lr;
            b2v[ct] = g_b2[n2];
            w30[ct] = g_w3[n2*3 + 0];
            w31[ct] = g_w3[n2*3 + 1];
            w32[ct] = g_w3[n2*3 + 2];
        }
        #pragma unroll
        for (int rt = 0; rt < 4; ++rt)
            #pragma unroll
            for (int r = 0; r < 4; ++r) {
                float s0 = 0.f, s1 = 0.f, s2 = 0.f;
                #pragma unroll
                for (int ct = 0; ct < 4; ++ct) {
                    const float v = fmaxf(acc2[rt][ct][r] + b2v[ct], 0.0f);
                    s0 = fmaf(v, w30[ct], s0);
                    s1 = fmaf(v, w31[ct], s1);
                    s2 = fmaf(v, w32[ct], s2);
                }
                #pragma unroll
                for (int off = 1; off < 16; off <<= 1) {
                    s0 += __shfl_xor(s0, off);
                    s1 += __shfl_xor(s1, off);
                    s2 += __shfl_xor(s2, off);
                }
                if (lr == 0) {
                    const int pt = wr*64 + rt*16 + lk*4 + r;
                    const int base = PRGB_OFF/4 + (wc*128 + pt)*3;
                    smf[base + 0] = s0;
                    smf[base + 1] = s1;
                    smf[base + 2] = s2;
                }
            }
    }
    __syncthreads();   // B4: prgb ready

    if (tid < 128) {
        const int p = tid;
        const float s0 = smf[p*3 + 0] + smf[(128 + p)*3 + 0] + g_b3[0];
        const float s1 = smf[p*3 + 1] + smf[(128 + p)*3 + 1] + g_b3[1];
        const float s2 = smf[p*3 + 2] + smf[(128 + p)*3 + 2] + g_b3[2];
        const int pt = ray*128 + p;
        out_rgb[pt*3 + 0] = 1.0f / (1.0f + expf(-s0));
        out_rgb[pt*3 + 1] = 1.0f / (1.0f + expf(-s1));
        out_rgb[pt*3 + 2] = 1.0f / (1.0f + expf(-s2));
    }
}

extern "C" void kernel_launch(void* const* d_in, const int* in_sizes, int n_in,
                              void* d_out, int out_size, void* d_ws, size_t ws_size,
                              hipStream_t stream)
{
    const float* g_org = (const float*)d_in[0];
    const float* g_dir = (const float*)d_in[1];
    const float* g_len = (const float*)d_in[2];
    const float* g_gd  = (const float*)d_in[3];
    const float* g_gc  = (const float*)d_in[4];
    const float* g_w1  = (const float*)d_in[5];
    const float* g_b1  = (const float*)d_in[6];
    const float* g_w2  = (const float*)d_in[7];
    const float* g_b2  = (const float*)d_in[8];
    const float* g_w3  = (const float*)d_in[9];
    const float* g_b3  = (const float*)d_in[10];
    float* out = (float*)d_out;

    __bf16* wsb = (__bf16*)d_ws;
    bf16x8* pack = (bf16x8*)((char*)d_ws + 49152);
    const size_t need = 49152 + (size_t)1000000 * 32;   // weights + packed grid

    dvgo_prep_w<<<96, 256, 0, stream>>>(g_w1, g_w2, wsb);
    if (ws_size >= need) {
        dvgo_prep_grid<<<3907, 256, 0, stream>>>(g_gd, g_gc, pack);
        dvgo_main<true><<<4096, 256, 0, stream>>>(g_org, g_dir, g_len, g_gd, g_gc,
                                                  g_b1, g_b2, g_w3, g_b3,
                                                  (const bf16x8*)d_ws, pack,
                                                  out, out + 4096*128);
    } else {
        dvgo_main<false><<<4096, 256, 0, stream>>>(g_org, g_dir, g_len, g_gd, g_gc,
                                                   g_b1, g_b2, g_w3, g_b3,
                                                   (const bf16x8*)d_ws, pack,
                                                   out, out + 4096*128);
    }
}

// Round 4
// 101.192 us; speedup vs baseline: 2.1222x; 1.4025x over previous
//
#include <hip/hip_runtime.h>
#include <hip/hip_bf16.h>
#include <math.h>

// DirectVoxGO fused forward, v4: barrier-free split pipeline.
// prep_w: w1/w2/w3(pad16) -> bf16 MFMA A-fragment order in ws.
// prep_emb: per-ray embedding table e[16..39] bf16[32] (k=12..15 live in feat).
// prep_grid: grids -> packed AoS bf16 [voxel][16ch] (32 B).
// G: 1 thread/point, no LDS/barriers: 16 b128 gathers -> alpha + feat[pt][16].
// M: 1 block/ray, 4 waves, ZERO barriers: each wave owns 32 pts = private 8KB
//    LDS slab. Swapped GEMMs D=[n][pt]: feat frags global->reg, GEMM1 -> h1
//    slab -> GEMM2 -> h2 slab -> GEMM3 (MFMA, w3 padded) -> sigmoid -> rgb.

typedef __bf16 bf16x4 __attribute__((ext_vector_type(4)));
typedef __bf16 bf16x8 __attribute__((ext_vector_type(8)));
typedef float  f32x4  __attribute__((ext_vector_type(4)));

#define ACT_SHIFT_F (-13.815509557964774f)

// ws layout (bytes): wf [0,53248) | emb 57344+4096*64 | pack 319488+32MB | feat
#define EMB_B   57344
#define PACK_B  319488
#define FEAT_B  33873920
#define NEED_FULL 50651136ull          // FEAT_B + 524288*32
#define NEED_PACK 33611776ull          // EMB_B + 32MB (fallback pack offset)

// ---------------- prep: weights -> fragment-linear bf16 ----------------
// elems [0,8192): w1 A-frags [ct=8][ks=2][lane][j=8], k>=39 zeroed
// elems [8192,24576): w2 A-frags [ct=8][ks=4][lane][j=8]
// elems [24576,26624): w3 A-frags [ks=4][lane][j=8], cols c>=3 zeroed
__global__ void dvgo_prep_w(const float* __restrict__ g_w1,
                            const float* __restrict__ g_w2,
                            const float* __restrict__ g_w3,
                            __bf16* __restrict__ wsb)
{
    const int idx = blockIdx.x * 256 + threadIdx.x;
    if (idx < 8192) {
        const int j = idx & 7, lane = (idx >> 3) & 63, ks = (idx >> 9) & 1, ct = idx >> 10;
        const int n = ct * 16 + (lane & 15);
        const int k = ks * 32 + ((lane >> 4) & 3) * 8 + j;
        wsb[idx] = (__bf16)((k < 39) ? g_w1[k * 128 + n] : 0.0f);
    } else if (idx < 24576) {
        const int i2 = idx - 8192;
        const int j = i2 & 7, lane = (i2 >> 3) & 63, ks = (i2 >> 9) & 3, ct = i2 >> 11;
        const int n = ct * 16 + (lane & 15);
        const int k = ks * 32 + ((lane >> 4) & 3) * 8 + j;
        wsb[idx] = (__bf16)g_w2[k * 128 + n];
    } else if (idx < 26624) {
        const int i3 = idx - 24576;
        const int j = i3 & 7, lane = (i3 >> 3) & 63, ks = i3 >> 9;
        const int c = lane & 15;
        const int k = ks * 32 + ((lane >> 4) & 3) * 8 + j;
        wsb[idx] = (__bf16)((c < 3) ? g_w3[k * 3 + c] : 0.0f);
    }
}

// ---------------- prep: per-ray embedding e[k=16..39] -> bf16[32] ----------------
__global__ void dvgo_prep_emb(const float* __restrict__ g_dir,
                              __bf16* __restrict__ emb)
{
    const int ray = blockIdx.x * 256 + threadIdx.x;
    if (ray >= 4096) return;
    const float d0 = g_dir[ray*3+0], d1 = g_dir[ray*3+1], d2 = g_dir[ray*3+2];
    __bf16 e[32];
    #pragma unroll
    for (int s = 0; s < 32; ++s) e[s] = (__bf16)0.0f;
    #pragma unroll
    for (int m = 0; m < 12; ++m) {
        const int i = m >> 2, j = m & 3;
        const float di = (i == 0) ? d0 : ((i == 1) ? d1 : d2);
        const float a = di * (float)(1 << j);
        if (m >= 1) e[m - 1] = (__bf16)sinf(a);    // k=16..26 (sin m=1..11)
        e[11 + m] = (__bf16)cosf(a);               // k=27..38 (cos m=0..11)
    }
    bf16x8* o = (bf16x8*)(emb + (size_t)ray * 32);
    #pragma unroll
    for (int q = 0; q < 4; ++q) {
        bf16x8 v;
        #pragma unroll
        for (int j = 0; j < 8; ++j) v[j] = e[q*8 + j];
        o[q] = v;
    }
}

// ---------------- prep: grids -> packed AoS bf16 [gi][16] ----------------
__global__ __launch_bounds__(256) void dvgo_prep_grid(const float* __restrict__ g_gd,
                                                      const float* __restrict__ g_gc,
                                                      bf16x8* __restrict__ pack)
{
    const int gi = blockIdx.x * 256 + threadIdx.x;
    if (gi >= 1000000) return;
    bf16x8 v0, v1;
    #pragma unroll
    for (int c = 0; c < 8; ++c) v0[c] = (__bf16)g_gc[c * 1000000 + gi];
    #pragma unroll
    for (int c = 0; c < 4; ++c) v1[c] = (__bf16)g_gc[(8 + c) * 1000000 + gi];
    v1[4] = (__bf16)g_gd[gi];
    v1[5] = (__bf16)0.0f; v1[6] = (__bf16)0.0f; v1[7] = (__bf16)0.0f;
    pack[gi * 2 + 0] = v0;
    pack[gi * 2 + 1] = v1;
}

// ---------------- G: gather, 1 thread/point, no LDS, no barriers ----------------
__global__ __launch_bounds__(256, 6)
void dvgo_gather(const float* __restrict__ g_org, const float* __restrict__ g_dir,
                 const float* __restrict__ g_len, const bf16x8* __restrict__ pack,
                 __bf16* __restrict__ feat, float* __restrict__ out_alpha)
{
    const int pt  = blockIdx.x * 256 + threadIdx.x;
    const int ray = pt >> 7;
    const float d0 = g_dir[ray*3+0], d1 = g_dir[ray*3+1], d2 = g_dir[ray*3+2];
    const float o0 = g_org[ray*3+0], o1 = g_org[ray*3+1], o2 = g_org[ray*3+2];
    const float len = g_len[pt];

    const float px = (o0 + d0*len + 1.0f) * 49.5f;
    const float py = (o1 + d1*len + 1.0f) * 49.5f;
    const float pz = (o2 + d2*len + 1.0f) * 49.5f;
    const float fx = floorf(px), fy = floorf(py), fz = floorf(pz);
    const int ix = (int)fx, iy = (int)fy, iz = (int)fz;
    const float qx = px - fx, qy = py - fy, qz = pz - fz;
    const float wxa[2] = {1.0f - qx, qx};
    const float wya[2] = {1.0f - qy, qy};
    const float wza[2] = {1.0f - qz, qz};
    const int  cxa[2] = {min(max(ix,0),99),   min(max(ix+1,0),99)};
    const int  cya[2] = {min(max(iy,0),99),   min(max(iy+1,0),99)};
    const int  cza[2] = {min(max(iz,0),99),   min(max(iz+1,0),99)};
    const bool vxa[2] = {(unsigned)ix < 100u, (unsigned)(ix+1) < 100u};
    const bool vya[2] = {(unsigned)iy < 100u, (unsigned)(iy+1) < 100u};
    const bool vza[2] = {(unsigned)iz < 100u, (unsigned)(iz+1) < 100u};

    float den = 0.0f;
    float cc[12];
    #pragma unroll
    for (int c = 0; c < 12; ++c) cc[c] = 0.0f;

    #pragma unroll
    for (int dz = 0; dz < 2; ++dz)
    #pragma unroll
    for (int dy = 0; dy < 2; ++dy)
    #pragma unroll
    for (int dx = 0; dx < 2; ++dx) {
        float w = wxa[dx] * wya[dy] * wza[dz];
        if (!(vxa[dx] && vya[dy] && vza[dz])) w = 0.0f;
        const int gi = (cza[dz]*100 + cya[dy])*100 + cxa[dx];
        const bf16x8 v0 = pack[gi*2 + 0];
        const bf16x8 v1 = pack[gi*2 + 1];
        #pragma unroll
        for (int c = 0; c < 8; ++c) cc[c]     += w * (float)v0[c];
        #pragma unroll
        for (int c = 0; c < 4; ++c) cc[8 + c] += w * (float)v1[c];
        den += w * (float)v1[4];
    }

    const float interval = sqrtf(d0*d0 + d1*d1 + d2*d2);
    const float e = expf(den + ACT_SHIFT_F);
    out_alpha[pt] = -expm1f(-interval * log1pf(e));

    bf16x8 f0, f1;
    #pragma unroll
    for (int c = 0; c < 8; ++c) f0[c] = (__bf16)cc[c];
    #pragma unroll
    for (int c = 0; c < 4; ++c) f1[c] = (__bf16)cc[8 + c];
    f1[4] = (__bf16)d0; f1[5] = (__bf16)d1; f1[6] = (__bf16)d2;
    f1[7] = (__bf16)sinf(d0);                  // e15 = sin(d0 * 1.0)
    bf16x8* fo = (bf16x8*)(feat + (size_t)pt * 16);
    fo[0] = f0;
    fo[1] = f1;
}

// ---------------- M: MLP, 1 block/ray, 4 waves, ZERO barriers ----------------
__global__ __launch_bounds__(256, 4)
void dvgo_mlp(const bf16x8* __restrict__ wf, const __bf16* __restrict__ emb,
              const __bf16* __restrict__ feat,
              const float* __restrict__ g_b1, const float* __restrict__ g_b2,
              const float* __restrict__ g_b3, float* __restrict__ out_rgb)
{
    __shared__ __align__(16) char smem[32768];   // [pt=128][n=128] bf16, swizzled
    const int tid  = threadIdx.x;
    const int ray  = blockIdx.x;
    const int lane = tid & 63;
    const int wid  = tid >> 6;
    const int lr   = lane & 15;
    const int lk   = lane >> 4;
    const int ptb  = wid * 32;                   // wave-private 32 rows of LDS

    // ---- embedding broadcasts + feat B-frags (global -> reg, no LDS) ----
    const bf16x8* ep = (const bf16x8*)(emb + (size_t)ray * 32);
    const bf16x8 ev0 = ep[0], ev1 = ep[1], ev2 = ep[2];
    bf16x8 zed;
    #pragma unroll
    for (int j = 0; j < 8; ++j) zed[j] = (__bf16)0.0f;

    bf16x8 fb0[2];
    #pragma unroll
    for (int rt = 0; rt < 2; ++rt) {
        const int pt = ray*128 + ptb + rt*16 + lr;
        const bf16x8 t = *(const bf16x8*)(feat + (size_t)pt*16 + (lk & 1)*8);
        fb0[rt] = (lk < 2) ? t : ((lk == 2) ? ev0 : ev1);
    }
    const bf16x8 fb1 = (lk == 0) ? ev2 : zed;

    // ---- GEMM1 (swapped): D[n1][pt] ----
    f32x4 acc1[2][8];
    #pragma unroll
    for (int rt = 0; rt < 2; ++rt)
        #pragma unroll
        for (int ct = 0; ct < 8; ++ct) acc1[rt][ct] = (f32x4){0.f,0.f,0.f,0.f};
    #pragma unroll
    for (int ct = 0; ct < 8; ++ct) {
        const bf16x8 aw0 = wf[(ct*2 + 0)*64 + lane];
        const bf16x8 aw1 = wf[(ct*2 + 1)*64 + lane];
        #pragma unroll
        for (int rt = 0; rt < 2; ++rt) {
            acc1[rt][ct] = __builtin_amdgcn_mfma_f32_16x16x32_bf16(aw0, fb0[rt], acc1[rt][ct], 0, 0, 0);
            acc1[rt][ct] = __builtin_amdgcn_mfma_f32_16x16x32_bf16(aw1, fb1,     acc1[rt][ct], 0, 0, 0);
        }
    }
    // h1[pt][n1] -> own slab (b64, swizzled)
    #pragma unroll
    for (int ct = 0; ct < 8; ++ct) {
        const f32x4 bv = *(const f32x4*)(g_b1 + ct*16 + lk*4);
        #pragma unroll
        for (int rt = 0; rt < 2; ++rt) {
            const int pt = ptb + rt*16 + lr;
            bf16x4 hv;
            #pragma unroll
            for (int r = 0; r < 4; ++r) hv[r] = (__bf16)fmaxf(acc1[rt][ct][r] + bv[r], 0.0f);
            const int a = (pt*256 + (ct*16 + lk*4)*2) ^ ((pt & 7) << 4);
            *(bf16x4*)(smem + a) = hv;
        }
    }

    // ---- GEMM2 (swapped): D[n2][pt]; reads/writes only this wave's slab ----
    bf16x8 hb[2][4];
    #pragma unroll
    for (int rt = 0; rt < 2; ++rt)
        #pragma unroll
        for (int ks = 0; ks < 4; ++ks) {
            const int pt = ptb + rt*16 + lr;
            const int a = (pt*256 + (ks*32 + lk*8)*2) ^ ((pt & 7) << 4);
            hb[rt][ks] = *(const bf16x8*)(smem + a);
        }
    f32x4 acc2[2][8];
    #pragma unroll
    for (int rt = 0; rt < 2; ++rt)
        #pragma unroll
        for (int ct = 0; ct < 8; ++ct) acc2[rt][ct] = (f32x4){0.f,0.f,0.f,0.f};
    #pragma unroll
    for (int ct = 0; ct < 8; ++ct)
        #pragma unroll
        for (int ks = 0; ks < 4; ++ks) {
            const bf16x8 aw = wf[1024 + (ct*4 + ks)*64 + lane];
            #pragma unroll
            for (int rt = 0; rt < 2; ++rt)
                acc2[rt][ct] = __builtin_amdgcn_mfma_f32_16x16x32_bf16(aw, hb[rt][ks], acc2[rt][ct], 0, 0, 0);
        }
    // h2[pt][n2] -> same slab (wave-private, LDS ops in-order within wave)
    #pragma unroll
    for (int ct = 0; ct < 8; ++ct) {
        const f32x4 bv = *(const f32x4*)(g_b2 + ct*16 + lk*4);
        #pragma unroll
        for (int rt = 0; rt < 2; ++rt) {
            const int pt = ptb + rt*16 + lr;
            bf16x4 hv;
            #pragma unroll
            for (int r = 0; r < 4; ++r) hv[r] = (__bf16)fmaxf(acc2[rt][ct][r] + bv[r], 0.0f);
            const int a = (pt*256 + (ct*16 + lk*4)*2) ^ ((pt & 7) << 4);
            *(bf16x4*)(smem + a) = hv;
        }
    }

    // ---- GEMM3 (swapped, w3 padded to 16): D[c][pt] ----
    bf16x8 h2b[2][4];
    #pragma unroll
    for (int rt = 0; rt < 2; ++rt)
        #pragma unroll
        for (int ks = 0; ks < 4; ++ks) {
            const int pt = ptb + rt*16 + lr;
            const int a = (pt*256 + (ks*32 + lk*8)*2) ^ ((pt & 7) << 4);
            h2b[rt][ks] = *(const bf16x8*)(smem + a);
        }
    f32x4 acc3[2];
    acc3[0] = (f32x4){0.f,0.f,0.f,0.f};
    acc3[1] = (f32x4){0.f,0.f,0.f,0.f};
    #pragma unroll
    for (int ks = 0; ks < 4; ++ks) {
        const bf16x8 aw = wf[3072 + ks*64 + lane];
        #pragma unroll
        for (int rt = 0; rt < 2; ++rt)
            acc3[rt] = __builtin_amdgcn_mfma_f32_16x16x32_bf16(aw, h2b[rt][ks], acc3[rt], 0, 0, 0);
    }
    if (lk == 0) {
        const float b30 = g_b3[0], b31 = g_b3[1], b32 = g_b3[2];
        #pragma unroll
        for (int rt = 0; rt < 2; ++rt) {
            const int pt = ray*128 + ptb + rt*16 + lr;
            out_rgb[pt*3 + 0] = 1.0f / (1.0f + expf(-(acc3[rt][0] + b30)));
            out_rgb[pt*3 + 1] = 1.0f / (1.0f + expf(-(acc3[rt][1] + b31)));
            out_rgb[pt*3 + 2] = 1.0f / (1.0f + expf(-(acc3[rt][2] + b32)));
        }
    }
}

// ================= fallback fused kernel (v3, proven) =================
#define FB_FEAT_OFF 0
#define FB_PCC_OFF  16384
#define FB_H1_OFF   0
#define FB_PRGB_OFF 0

template <bool PACKED>
__global__ __launch_bounds__(256, 4)
void dvgo_main(const float* __restrict__ g_org, const float* __restrict__ g_dir,
               const float* __restrict__ g_len, const float* __restrict__ g_gd,
               const float* __restrict__ g_gc, const float* __restrict__ g_b1,
               const float* __restrict__ g_b2, const float* __restrict__ g_w3,
               const float* __restrict__ g_b3, const bf16x8* __restrict__ wf,
               const bf16x8* __restrict__ g_pack,
               float* __restrict__ out_alpha, float* __restrict__ out_rgb)
{
    __shared__ __align__(16) char smem[32768];
    float* smf = (float*)smem;
    const int tid = threadIdx.x;
    const int ray = blockIdx.x;
    const float d0 = g_dir[ray*3+0], d1 = g_dir[ray*3+1], d2 = g_dir[ray*3+2];
    {
        const float o0 = g_org[ray*3+0], o1 = g_org[ray*3+1], o2 = g_org[ray*3+2];
        const int p = tid & 127;
        const int dzv = tid >> 7;
        const float len = g_len[ray*128 + p];
        const float px = (o0 + d0*len + 1.0f) * 49.5f;
        const float py = (o1 + d1*len + 1.0f) * 49.5f;
        const float pz = (o2 + d2*len + 1.0f) * 49.5f;
        const float fx = floorf(px), fy = floorf(py), fz = floorf(pz);
        const int ix = (int)fx, iy = (int)fy, iz0 = (int)fz;
        const float qx = px - fx, qy = py - fy, qz = pz - fz;
        const float wxa[2] = {1.0f - qx, qx};
        const float wya[2] = {1.0f - qy, qy};
        const int  cxa[2] = {min(max(ix,0),99),   min(max(ix+1,0),99)};
        const int  cya[2] = {min(max(iy,0),99),   min(max(iy+1,0),99)};
        const bool vxa[2] = {(unsigned)ix < 100u, (unsigned)(ix+1) < 100u};
        const bool vya[2] = {(unsigned)iy < 100u, (unsigned)(iy+1) < 100u};
        const int  iz = iz0 + dzv;
        const float wz = dzv ? qz : (1.0f - qz);
        const int  cz = min(max(iz,0),99);
        const bool vz = (unsigned)iz < 100u;
        float den = 0.0f;
        float cc[12];
        #pragma unroll
        for (int c = 0; c < 12; ++c) cc[c] = 0.0f;
        #pragma unroll
        for (int dy = 0; dy < 2; ++dy)
        #pragma unroll
        for (int dx = 0; dx < 2; ++dx) {
            float w = wxa[dx] * wya[dy] * wz;
            if (!(vxa[dx] && vya[dy] && vz)) w = 0.0f;
            const int gi = (cz*100 + cya[dy])*100 + cxa[dx];
            if (PACKED) {
                const bf16x8 v0 = g_pack[gi*2 + 0];
                const bf16x8 v1 = g_pack[gi*2 + 1];
                #pragma unroll
                for (int c = 0; c < 8; ++c) cc[c]     += w * (float)v0[c];
                #pragma unroll
                for (int c = 0; c < 4; ++c) cc[8 + c] += w * (float)v1[c];
                den += w * (float)v1[4];
            } else {
                den += w * g_gd[gi];
                #pragma unroll
                for (int c = 0; c < 12; ++c) cc[c] += w * g_gc[c*1000000 + gi];
            }
        }
        if (dzv) {
            #pragma unroll
            for (int c = 0; c < 12; ++c) smf[FB_PCC_OFF/4 + p*13 + c] = cc[c];
            smf[FB_PCC_OFF/4 + p*13 + 12] = den;
        }
        __syncthreads();
        if (!dzv) {
            #pragma unroll
            for (int c = 0; c < 12; ++c) cc[c] += smf[FB_PCC_OFF/4 + p*13 + c];
            den += smf[FB_PCC_OFF/4 + p*13 + 12];
            const float interval = sqrtf(d0*d0 + d1*d1 + d2*d2);
            const float e = expf(den + ACT_SHIFT_F);
            out_alpha[ray*128 + p] = -expm1f(-interval * log1pf(e));
            bf16x8 f0; bf16x4 f1;
            #pragma unroll
            for (int c = 0; c < 8; ++c) f0[c] = (__bf16)cc[c];
            #pragma unroll
            for (int c = 0; c < 4; ++c) f1[c] = (__bf16)cc[8+c];
            const int swz = (p & 7) << 4;
            *reinterpret_cast<bf16x8*>(smem + ((FB_FEAT_OFF + p*128 +  0) ^ swz)) = f0;
            *reinterpret_cast<bf16x4*>(smem + ((FB_FEAT_OFF + p*128 + 16) ^ swz)) = f1;
        } else {
            float vals[52];
            vals[0] = d0; vals[1] = d1; vals[2] = d2;
            #pragma unroll
            for (int i = 0; i < 3; ++i) {
                const float di = (i == 0) ? d0 : ((i == 1) ? d1 : d2);
                #pragma unroll
                for (int j = 0; j < 4; ++j) {
                    const float a = di * (float)(1 << j);
                    vals[3  + i*4 + j] = sinf(a);
                    vals[15 + i*4 + j] = cosf(a);
                }
            }
            #pragma unroll
            for (int c = 27; c < 52; ++c) vals[c] = 0.0f;
            const int swz = (p & 7) << 4;
            #pragma unroll
            for (int i = 0; i < 13; ++i) {
                bf16x4 v4;
                #pragma unroll
                for (int r = 0; r < 4; ++r) v4[r] = (__bf16)vals[i*4 + r];
                *reinterpret_cast<bf16x4*>(smem + ((FB_FEAT_OFF + p*128 + 24 + i*8) ^ swz)) = v4;
            }
        }
    }
    __syncthreads();
    const int lane = tid & 63;
    const int wid  = tid >> 6;
    const int lr   = lane & 15;
    const int lk   = lane >> 4;
    {
        bf16x8 bf[2][2];
        #pragma unroll
        for (int rt = 0; rt < 2; ++rt)
            #pragma unroll
            for (int ks = 0; ks < 2; ++ks) {
                const int pt = wid*32 + rt*16 + lr;
                int a = FB_FEAT_OFF + pt*128 + ks*64 + lk*16; a ^= (pt & 7) << 4;
                bf[rt][ks] = *reinterpret_cast<const bf16x8*>(smem + a);
            }
        __syncthreads();
        f32x4 acc1[2][8];
        #pragma unroll
        for (int rt = 0; rt < 2; ++rt)
            #pragma unroll
            for (int ct = 0; ct < 8; ++ct) acc1[rt][ct] = (f32x4){0.f,0.f,0.f,0.f};
        #pragma unroll
        for (int ct = 0; ct < 8; ++ct) {
            const bf16x8 aw0 = wf[(ct*2 + 0)*64 + lane];
            const bf16x8 aw1 = wf[(ct*2 + 1)*64 + lane];
            #pragma unroll
            for (int rt = 0; rt < 2; ++rt) {
                acc1[rt][ct] = __builtin_amdgcn_mfma_f32_16x16x32_bf16(aw0, bf[rt][0], acc1[rt][ct], 0, 0, 0);
                acc1[rt][ct] = __builtin_amdgcn_mfma_f32_16x16x32_bf16(aw1, bf[rt][1], acc1[rt][ct], 0, 0, 0);
            }
        }
        #pragma unroll
        for (int ct = 0; ct < 8; ++ct) {
            const f32x4 b1v = *reinterpret_cast<const f32x4*>(g_b1 + ct*16 + lk*4);
            #pragma unroll
            for (int rt = 0; rt < 2; ++rt) {
                const int pt = wid*32 + rt*16 + lr;
                bf16x4 hv;
                #pragma unroll
                for (int r = 0; r < 4; ++r)
                    hv[r] = (__bf16)fmaxf(acc1[rt][ct][r] + b1v[r], 0.0f);
                int a = FB_H1_OFF + pt*256 + ct*32 + lk*8; a ^= (pt & 7) << 4;
                *reinterpret_cast<bf16x4*>(smem + a) = hv;
            }
        }
    }
    __syncthreads();
    const int wr = wid >> 1, wc = wid & 1;
    f32x4 acc2[4][4];
    #pragma unroll
    for (int rt = 0; rt < 4; ++rt)
        #pragma unroll
        for (int ct = 0; ct < 4; ++ct) acc2[rt][ct] = (f32x4){0.f,0.f,0.f,0.f};
    #pragma unroll
    for (int ks = 0; ks < 4; ++ks) {
        bf16x8 a2[4];
        #pragma unroll
        for (int rt = 0; rt < 4; ++rt) {
            const int pt = wr*64 + rt*16 + lr;
            int a = FB_H1_OFF + pt*256 + ks*64 + lk*16; a ^= (pt & 7) << 4;
            a2[rt] = *reinterpret_cast<const bf16x8*>(smem + a);
        }
        #pragma unroll
        for (int ct = 0; ct < 4; ++ct) {
            const int ctg = wc*4 + ct;
            const bf16x8 b2f = wf[1024 + (ctg*4 + ks)*64 + lane];
            #pragma unroll
            for (int rt = 0; rt < 4; ++rt)
                acc2[rt][ct] = __builtin_amdgcn_mfma_f32_16x16x32_bf16(a2[rt], b2f, acc2[rt][ct], 0, 0, 0);
        }
    }
    __syncthreads();
    {
        float b2v[4], w30[4], w31[4], w32[4];
        #pragma unroll
        for (int ct = 0; ct < 4; ++ct) {
            const int n2 = wc*64 + ct*16 + lr;
            b2v[ct] = g_b2[n2];
            w30[ct] = g_w3[n2*3 + 0];
            w31[ct] = g_w3[n2*3 + 1];
            w32[ct] = g_w3[n2*3 + 2];
        }
        #pragma unroll
        for (int rt = 0; rt < 4; ++rt)
            #pragma unroll
            for (int r = 0; r < 4; ++r) {
                float s0 = 0.f, s1 = 0.f, s2 = 0.f;
                #pragma unroll
                for (int ct = 0; ct < 4; ++ct) {
                    const float v = fmaxf(acc2[rt][ct][r] + b2v[ct], 0.0f);
                    s0 = fmaf(v, w30[ct], s0);
                    s1 = fmaf(v, w31[ct], s1);
                    s2 = fmaf(v, w32[ct], s2);
                }
                #pragma unroll
                for (int off = 1; off < 16; off <<= 1) {
                    s0 += __shfl_xor(s0, off);
                    s1 += __shfl_xor(s1, off);
                    s2 += __shfl_xor(s2, off);
                }
                if (lr == 0) {
                    const int pt = wr*64 + rt*16 + lk*4 + r;
                    const int base = FB_PRGB_OFF/4 + (wc*128 + pt)*3;
                    smf[base + 0] = s0;
                    smf[base + 1] = s1;
                    smf[base + 2] = s2;
                }
            }
    }
    __syncthreads();
    if (tid < 128) {
        const int p = tid;
        const float s0 = smf[p*3 + 0] + smf[(128 + p)*3 + 0] + g_b3[0];
        const float s1 = smf[p*3 + 1] + smf[(128 + p)*3 + 1] + g_b3[1];
        const float s2 = smf[p*3 + 2] + smf[(128 + p)*3 + 2] + g_b3[2];
        const int pt = ray*128 + p;
        out_rgb[pt*3 + 0] = 1.0f / (1.0f + expf(-s0));
        out_rgb[pt*3 + 1] = 1.0f / (1.0f + expf(-s1));
        out_rgb[pt*3 + 2] = 1.0f / (1.0f + expf(-s2));
    }
}

extern "C" void kernel_launch(void* const* d_in, const int* in_sizes, int n_in,
                              void* d_out, int out_size, void* d_ws, size_t ws_size,
                              hipStream_t stream)
{
    const float* g_org = (const float*)d_in[0];
    const float* g_dir = (const float*)d_in[1];
    const float* g_len = (const float*)d_in[2];
    const float* g_gd  = (const float*)d_in[3];
    const float* g_gc  = (const float*)d_in[4];
    const float* g_w1  = (const float*)d_in[5];
    const float* g_b1  = (const float*)d_in[6];
    const float* g_w2  = (const float*)d_in[7];
    const float* g_b2  = (const float*)d_in[8];
    const float* g_w3  = (const float*)d_in[9];
    const float* g_b3  = (const float*)d_in[10];
    float* out = (float*)d_out;

    __bf16* wsb = (__bf16*)d_ws;
    dvgo_prep_w<<<104, 256, 0, stream>>>(g_w1, g_w2, g_w3, wsb);

    if (ws_size >= NEED_FULL) {
        __bf16* emb  = (__bf16*)((char*)d_ws + EMB_B);
        bf16x8* pack = (bf16x8*)((char*)d_ws + PACK_B);
        __bf16* feat = (__bf16*)((char*)d_ws + FEAT_B);
        dvgo_prep_emb<<<16, 256, 0, stream>>>(g_dir, emb);
        dvgo_prep_grid<<<3907, 256, 0, stream>>>(g_gd, g_gc, pack);
        dvgo_gather<<<2048, 256, 0, stream>>>(g_org, g_dir, g_len, pack, feat, out);
        dvgo_mlp<<<4096, 256, 0, stream>>>((const bf16x8*)wsb, emb, feat,
                                           g_b1, g_b2, g_b3, out + 4096*128);
    } else if (ws_size >= NEED_PACK) {
        bf16x8* pack = (bf16x8*)((char*)d_ws + EMB_B);
        dvgo_prep_grid<<<3907, 256, 0, stream>>>(g_gd, g_gc, pack);
        dvgo_main<true><<<4096, 256, 0, stream>>>(g_org, g_dir, g_len, g_gd, g_gc,
                                                  g_b1, g_b2, g_w3, g_b3,
                                                  (const bf16x8*)wsb, pack,
                                                  out, out + 4096*128);
    } else {
        dvgo_main<false><<<4096, 256, 0, stream>>>(g_org, g_dir, g_len, g_gd, g_gc,
                                                   g_b1, g_b2, g_w3, g_b3,
                                                   (const bf16x8*)wsb, nullptr,
                                                   out, out + 4096*128);
    }
}

// Round 5
// 83.403 us; speedup vs baseline: 2.5748x; 1.2133x over previous
//
#include <hip/hip_runtime.h>
#include <hip/hip_bf16.h>
#include <math.h>

// DirectVoxGO fused forward, v5.
// prep (merged): grids -> packed AoS bf16 [voxel][16ch] (32 B)  +  w1/w2/w3 ->
//   bf16 MFMA A-fragment order in ws.
// G: 1 thread/point, no LDS/barriers: 16 b128 gathers -> alpha + feat[pt][16].
// M (new): 1 block/ray, 4 waves slice the N dimension (32 n each) over ALL 128
//   pts -> each weight fragment loaded ONCE per block (64KB/block vs 208KB in
//   v4). Activations via shared 32KB h-tile + 3 barriers. Embedding k>=16
//   computed in-kernel per lane (each lane owns one 8-wide k-slot).

typedef __bf16 bf16x4 __attribute__((ext_vector_type(4)));
typedef __bf16 bf16x8 __attribute__((ext_vector_type(8)));
typedef float  f32x4  __attribute__((ext_vector_type(4)));

#define ACT_SHIFT_F (-13.815509557964774f)

// ws layout (bytes): wf [0,53248) | pack [53248, +32MB) | feat [32053248, +16MB)
#define PACK_B  53248
#define FEAT_B  32053248
#define NEED_FULL 48830464ull
#define NEED_PACK 32053248ull

// ---------------- prep: grid pack + weight fragments ----------------
// weight elems [0,8192): w1 A-frags [ct=8][ks=2][lane][j=8], k>=39 zeroed
// elems [8192,24576): w2 A-frags [ct=8][ks=4][lane][j=8]
// elems [24576,26624): w3 A-frags [ks=4][lane][j=8], cols c>=3 zeroed
__global__ __launch_bounds__(256)
void dvgo_prep(const float* __restrict__ g_gd, const float* __restrict__ g_gc,
               const float* __restrict__ g_w1, const float* __restrict__ g_w2,
               const float* __restrict__ g_w3, bf16x8* __restrict__ pack,
               __bf16* __restrict__ wsb, int wbase)
{
    const int bid = blockIdx.x;
    if (bid < wbase) {
        const int gi = bid * 256 + threadIdx.x;
        if (gi >= 1000000) return;
        bf16x8 v0, v1;
        #pragma unroll
        for (int c = 0; c < 8; ++c) v0[c] = (__bf16)g_gc[c * 1000000 + gi];
        #pragma unroll
        for (int c = 0; c < 4; ++c) v1[c] = (__bf16)g_gc[(8 + c) * 1000000 + gi];
        v1[4] = (__bf16)g_gd[gi];
        v1[5] = (__bf16)0.0f; v1[6] = (__bf16)0.0f; v1[7] = (__bf16)0.0f;
        pack[gi * 2 + 0] = v0;
        pack[gi * 2 + 1] = v1;
        return;
    }
    const int idx = (bid - wbase) * 256 + threadIdx.x;
    if (idx < 8192) {
        const int j = idx & 7, lane = (idx >> 3) & 63, ks = (idx >> 9) & 1, ct = idx >> 10;
        const int n = ct * 16 + (lane & 15);
        const int k = ks * 32 + ((lane >> 4) & 3) * 8 + j;
        wsb[idx] = (__bf16)((k < 39) ? g_w1[k * 128 + n] : 0.0f);
    } else if (idx < 24576) {
        const int i2 = idx - 8192;
        const int j = i2 & 7, lane = (i2 >> 3) & 63, ks = (i2 >> 9) & 3, ct = i2 >> 11;
        const int n = ct * 16 + (lane & 15);
        const int k = ks * 32 + ((lane >> 4) & 3) * 8 + j;
        wsb[idx] = (__bf16)g_w2[k * 128 + n];
    } else if (idx < 26624) {
        const int i3 = idx - 24576;
        const int j = i3 & 7, lane = (i3 >> 3) & 63, ks = i3 >> 9;
        const int c = lane & 15;
        const int k = ks * 32 + ((lane >> 4) & 3) * 8 + j;
        wsb[idx] = (__bf16)((c < 3) ? g_w3[k * 3 + c] : 0.0f);
    }
}

// ---------------- G: gather, 1 thread/point, no LDS, no barriers ----------------
__global__ __launch_bounds__(256, 6)
void dvgo_gather(const float* __restrict__ g_org, const float* __restrict__ g_dir,
                 const float* __restrict__ g_len, const bf16x8* __restrict__ pack,
                 __bf16* __restrict__ feat, float* __restrict__ out_alpha)
{
    const int pt  = blockIdx.x * 256 + threadIdx.x;
    const int ray = pt >> 7;
    const float d0 = g_dir[ray*3+0], d1 = g_dir[ray*3+1], d2 = g_dir[ray*3+2];
    const float o0 = g_org[ray*3+0], o1 = g_org[ray*3+1], o2 = g_org[ray*3+2];
    const float len = g_len[pt];

    const float px = (o0 + d0*len + 1.0f) * 49.5f;
    const float py = (o1 + d1*len + 1.0f) * 49.5f;
    const float pz = (o2 + d2*len + 1.0f) * 49.5f;
    const float fx = floorf(px), fy = floorf(py), fz = floorf(pz);
    const int ix = (int)fx, iy = (int)fy, iz = (int)fz;
    const float qx = px - fx, qy = py - fy, qz = pz - fz;
    const float wxa[2] = {1.0f - qx, qx};
    const float wya[2] = {1.0f - qy, qy};
    const float wza[2] = {1.0f - qz, qz};
    const int  cxa[2] = {min(max(ix,0),99),   min(max(ix+1,0),99)};
    const int  cya[2] = {min(max(iy,0),99),   min(max(iy+1,0),99)};
    const int  cza[2] = {min(max(iz,0),99),   min(max(iz+1,0),99)};
    const bool vxa[2] = {(unsigned)ix < 100u, (unsigned)(ix+1) < 100u};
    const bool vya[2] = {(unsigned)iy < 100u, (unsigned)(iy+1) < 100u};
    const bool vza[2] = {(unsigned)iz < 100u, (unsigned)(iz+1) < 100u};

    float den = 0.0f;
    float cc[12];
    #pragma unroll
    for (int c = 0; c < 12; ++c) cc[c] = 0.0f;

    #pragma unroll
    for (int dz = 0; dz < 2; ++dz)
    #pragma unroll
    for (int dy = 0; dy < 2; ++dy)
    #pragma unroll
    for (int dx = 0; dx < 2; ++dx) {
        float w = wxa[dx] * wya[dy] * wza[dz];
        if (!(vxa[dx] && vya[dy] && vza[dz])) w = 0.0f;
        const int gi = (cza[dz]*100 + cya[dy])*100 + cxa[dx];
        const bf16x8 v0 = pack[gi*2 + 0];
        const bf16x8 v1 = pack[gi*2 + 1];
        #pragma unroll
        for (int c = 0; c < 8; ++c) cc[c]     += w * (float)v0[c];
        #pragma unroll
        for (int c = 0; c < 4; ++c) cc[8 + c] += w * (float)v1[c];
        den += w * (float)v1[4];
    }

    const float interval = sqrtf(d0*d0 + d1*d1 + d2*d2);
    const float e = expf(den + ACT_SHIFT_F);
    out_alpha[pt] = -expm1f(-interval * log1pf(e));

    bf16x8 f0, f1;
    #pragma unroll
    for (int c = 0; c < 8; ++c) f0[c] = (__bf16)cc[c];
    #pragma unroll
    for (int c = 0; c < 4; ++c) f1[c] = (__bf16)cc[8 + c];
    f1[4] = (__bf16)d0; f1[5] = (__bf16)d1; f1[6] = (__bf16)d2;
    f1[7] = (__bf16)sinf(d0);                  // k=15 = sin(d0 * 1.0)
    bf16x8* fo = (bf16x8*)(feat + (size_t)pt * 16);
    fo[0] = f0;
    fo[1] = f1;
}

// ---------------- M: MLP, 1 block/ray, waves slice N ----------------
__global__ __launch_bounds__(256, 3)
void dvgo_mlp(const bf16x8* __restrict__ wf, const __bf16* __restrict__ feat,
              const float* __restrict__ g_dir,
              const float* __restrict__ g_b1, const float* __restrict__ g_b2,
              const float* __restrict__ g_b3, float* __restrict__ out_rgb)
{
    __shared__ __align__(16) char smem[32768];   // h[pt=128][n=128] bf16, swizzled
    const int tid  = threadIdx.x;
    const int ray  = blockIdx.x;
    const int lane = tid & 63;
    const int wid  = tid >> 6;
    const int lr   = lane & 15;
    const int lk   = lane >> 4;

    const float d0 = g_dir[ray*3+0], d1 = g_dir[ray*3+1], d2 = g_dir[ray*3+2];

    // ---- per-lane embedding slot (k = kbase..kbase+7) ----
    // ks0 frag: k = lk*8+j -> lk 0,1 from feat; lk 2,3 from emb.
    // ks1 frag: k = 32+j -> lk==0 from emb (k<=38), else zero.
    const int kbase = (lk >= 2) ? lk * 8 : 32;
    bf16x8 eqv;
    #pragma unroll
    for (int j = 0; j < 8; ++j) {
        const int k = kbase + j;
        const bool is_sin = (k >= 16) && (k <= 26);
        const bool is_cos = (k >= 27) && (k <= 38);
        const int m = is_sin ? (k - 15) : (k - 27);
        const int mi = m >> 2;
        const float di = (mi == 0) ? d0 : ((mi == 1) ? d1 : d2);
        const float a = di * (float)(1 << (m & 3));
        float v = is_sin ? sinf(a) : cosf(a);
        if (!is_sin && !is_cos) v = 0.0f;
        eqv[j] = (__bf16)v;
    }
    bf16x8 zed;
    #pragma unroll
    for (int j = 0; j < 8; ++j) zed[j] = (__bf16)0.0f;
    const bf16x8 bq1 = (lk == 0) ? eqv : zed;    // ks1 B-frag, pt-independent

    // ---- feat loads: all 8 pt-tiles (b128 each; lanes lk>=2 use safe addr) ----
    bf16x8 ft[8];
    #pragma unroll
    for (int rt = 0; rt < 8; ++rt) {
        const int pt = ray*128 + rt*16 + lr;
        ft[rt] = *(const bf16x8*)(feat + (size_t)pt*16 + (lk >= 1 ? 8 : 0));
    }

    // ---- GEMM1: this wave's n1-slice (2 ct tiles) x all 128 pts ----
    bf16x8 aw1[2][2];
    #pragma unroll
    for (int c2 = 0; c2 < 2; ++c2)
        #pragma unroll
        for (int ks = 0; ks < 2; ++ks)
            aw1[c2][ks] = wf[((wid*2 + c2)*2 + ks)*64 + lane];

    f32x4 acc1[8][2];
    #pragma unroll
    for (int rt = 0; rt < 8; ++rt)
        #pragma unroll
        for (int c2 = 0; c2 < 2; ++c2) acc1[rt][c2] = (f32x4){0.f,0.f,0.f,0.f};
    #pragma unroll
    for (int rt = 0; rt < 8; ++rt) {
        const bf16x8 b0 = (lk < 2) ? ft[rt] : eqv;
        #pragma unroll
        for (int c2 = 0; c2 < 2; ++c2) {
            acc1[rt][c2] = __builtin_amdgcn_mfma_f32_16x16x32_bf16(aw1[c2][0], b0,  acc1[rt][c2], 0, 0, 0);
            acc1[rt][c2] = __builtin_amdgcn_mfma_f32_16x16x32_bf16(aw1[c2][1], bq1, acc1[rt][c2], 0, 0, 0);
        }
    }

    // hoist GEMM2 weight loads (L2) so latency hides under stores+barrier
    bf16x8 aw2[2][4];
    #pragma unroll
    for (int c2 = 0; c2 < 2; ++c2)
        #pragma unroll
        for (int ks = 0; ks < 4; ++ks)
            aw2[c2][ks] = wf[1024 + ((wid*2 + c2)*4 + ks)*64 + lane];

    // h1[pt][n1] -> LDS (+b1, relu)
    #pragma unroll
    for (int c2 = 0; c2 < 2; ++c2) {
        const int nb = (wid*2 + c2)*16 + lk*4;
        const f32x4 bv = *(const f32x4*)(g_b1 + nb);
        #pragma unroll
        for (int rt = 0; rt < 8; ++rt) {
            const int pt = rt*16 + lr;
            bf16x4 hv;
            #pragma unroll
            for (int r = 0; r < 4; ++r) hv[r] = (__bf16)fmaxf(acc1[rt][c2][r] + bv[r], 0.0f);
            const int a = (pt*256 + nb*2) ^ ((pt & 7) << 4);
            *(bf16x4*)(smem + a) = hv;
        }
    }
    __syncthreads();   // B1: h1 complete

    // ---- GEMM2: this wave's n2-slice x all pts; B = h1 from LDS ----
    f32x4 acc2[8][2];
    #pragma unroll
    for (int rt = 0; rt < 8; ++rt)
        #pragma unroll
        for (int c2 = 0; c2 < 2; ++c2) acc2[rt][c2] = (f32x4){0.f,0.f,0.f,0.f};
    #pragma unroll
    for (int rt = 0; rt < 8; ++rt) {
        const int pt = rt*16 + lr;
        const int base = pt*256, sz = (pt & 7) << 4;
        bf16x8 hq[4];
        #pragma unroll
        for (int ks = 0; ks < 4; ++ks)
            hq[ks] = *(const bf16x8*)(smem + ((base + (ks*32 + lk*8)*2) ^ sz));
        #pragma unroll
        for (int c2 = 0; c2 < 2; ++c2)
            #pragma unroll
            for (int ks = 0; ks < 4; ++ks)
                acc2[rt][c2] = __builtin_amdgcn_mfma_f32_16x16x32_bf16(aw2[c2][ks], hq[ks], acc2[rt][c2], 0, 0, 0);
    }

    bf16x8 aw3[4];
    #pragma unroll
    for (int ks = 0; ks < 4; ++ks) aw3[ks] = wf[3072 + ks*64 + lane];

    __syncthreads();   // B2: all h1 reads done; safe to overwrite with h2

    #pragma unroll
    for (int c2 = 0; c2 < 2; ++c2) {
        const int nb = (wid*2 + c2)*16 + lk*4;
        const f32x4 bv = *(const f32x4*)(g_b2 + nb);
        #pragma unroll
        for (int rt = 0; rt < 8; ++rt) {
            const int pt = rt*16 + lr;
            bf16x4 hv;
            #pragma unroll
            for (int r = 0; r < 4; ++r) hv[r] = (__bf16)fmaxf(acc2[rt][c2][r] + bv[r], 0.0f);
            const int a = (pt*256 + nb*2) ^ ((pt & 7) << 4);
            *(bf16x4*)(smem + a) = hv;
        }
    }
    __syncthreads();   // B3: h2 complete

    // ---- GEMM3: wave's own 2 pt-tiles, w3 padded to 16 cols ----
    f32x4 acc3[2];
    acc3[0] = (f32x4){0.f,0.f,0.f,0.f};
    acc3[1] = (f32x4){0.f,0.f,0.f,0.f};
    #pragma unroll
    for (int q = 0; q < 2; ++q) {
        const int pt = (wid*2 + q)*16 + lr;
        const int base = pt*256, sz = (pt & 7) << 4;
        #pragma unroll
        for (int ks = 0; ks < 4; ++ks) {
            const bf16x8 hq = *(const bf16x8*)(smem + ((base + (ks*32 + lk*8)*2) ^ sz));
            acc3[q] = __builtin_amdgcn_mfma_f32_16x16x32_bf16(aw3[ks], hq, acc3[q], 0, 0, 0);
        }
    }
    if (lk == 0) {
        const float b30 = g_b3[0], b31 = g_b3[1], b32 = g_b3[2];
        #pragma unroll
        for (int q = 0; q < 2; ++q) {
            const int pt = ray*128 + (wid*2 + q)*16 + lr;
            out_rgb[pt*3 + 0] = 1.0f / (1.0f + expf(-(acc3[q][0] + b30)));
            out_rgb[pt*3 + 1] = 1.0f / (1.0f + expf(-(acc3[q][1] + b31)));
            out_rgb[pt*3 + 2] = 1.0f / (1.0f + expf(-(acc3[q][2] + b32)));
        }
    }
}

// ================= fallback fused kernel (v3, proven) =================
#define FB_FEAT_OFF 0
#define FB_PCC_OFF  16384
#define FB_H1_OFF   0
#define FB_PRGB_OFF 0

template <bool PACKED>
__global__ __launch_bounds__(256, 4)
void dvgo_main(const float* __restrict__ g_org, const float* __restrict__ g_dir,
               const float* __restrict__ g_len, const float* __restrict__ g_gd,
               const float* __restrict__ g_gc, const float* __restrict__ g_b1,
               const float* __restrict__ g_b2, const float* __restrict__ g_w3,
               const float* __restrict__ g_b3, const bf16x8* __restrict__ wf,
               const bf16x8* __restrict__ g_pack,
               float* __restrict__ out_alpha, float* __restrict__ out_rgb)
{
    __shared__ __align__(16) char smem[32768];
    float* smf = (float*)smem;
    const int tid = threadIdx.x;
    const int ray = blockIdx.x;
    const float d0 = g_dir[ray*3+0], d1 = g_dir[ray*3+1], d2 = g_dir[ray*3+2];
    {
        const float o0 = g_org[ray*3+0], o1 = g_org[ray*3+1], o2 = g_org[ray*3+2];
        const int p = tid & 127;
        const int dzv = tid >> 7;
        const float len = g_len[ray*128 + p];
        const float px = (o0 + d0*len + 1.0f) * 49.5f;
        const float py = (o1 + d1*len + 1.0f) * 49.5f;
        const float pz = (o2 + d2*len + 1.0f) * 49.5f;
        const float fx = floorf(px), fy = floorf(py), fz = floorf(pz);
        const int ix = (int)fx, iy = (int)fy, iz0 = (int)fz;
        const float qx = px - fx, qy = py - fy, qz = pz - fz;
        const float wxa[2] = {1.0f - qx, qx};
        const float wya[2] = {1.0f - qy, qy};
        const int  cxa[2] = {min(max(ix,0),99),   min(max(ix+1,0),99)};
        const int  cya[2] = {min(max(iy,0),99),   min(max(iy+1,0),99)};
        const bool vxa[2] = {(unsigned)ix < 100u, (unsigned)(ix+1) < 100u};
        const bool vya[2] = {(unsigned)iy < 100u, (unsigned)(iy+1) < 100u};
        const int  iz = iz0 + dzv;
        const float wz = dzv ? qz : (1.0f - qz);
        const int  cz = min(max(iz,0),99);
        const bool vz = (unsigned)iz < 100u;
        float den = 0.0f;
        float cc[12];
        #pragma unroll
        for (int c = 0; c < 12; ++c) cc[c] = 0.0f;
        #pragma unroll
        for (int dy = 0; dy < 2; ++dy)
        #pragma unroll
        for (int dx = 0; dx < 2; ++dx) {
            float w = wxa[dx] * wya[dy] * wz;
            if (!(vxa[dx] && vya[dy] && vz)) w = 0.0f;
            const int gi = (cz*100 + cya[dy])*100 + cxa[dx];
            if (PACKED) {
                const bf16x8 v0 = g_pack[gi*2 + 0];
                const bf16x8 v1 = g_pack[gi*2 + 1];
                #pragma unroll
                for (int c = 0; c < 8; ++c) cc[c]     += w * (float)v0[c];
                #pragma unroll
                for (int c = 0; c < 4; ++c) cc[8 + c] += w * (float)v1[c];
                den += w * (float)v1[4];
            } else {
                den += w * g_gd[gi];
                #pragma unroll
                for (int c = 0; c < 12; ++c) cc[c] += w * g_gc[c*1000000 + gi];
            }
        }
        if (dzv) {
            #pragma unroll
            for (int c = 0; c < 12; ++c) smf[FB_PCC_OFF/4 + p*13 + c] = cc[c];
            smf[FB_PCC_OFF/4 + p*13 + 12] = den;
        }
        __syncthreads();
        if (!dzv) {
            #pragma unroll
            for (int c = 0; c < 12; ++c) cc[c] += smf[FB_PCC_OFF/4 + p*13 + c];
            den += smf[FB_PCC_OFF/4 + p*13 + 12];
            const float interval = sqrtf(d0*d0 + d1*d1 + d2*d2);
            const float e = expf(den + ACT_SHIFT_F);
            out_alpha[ray*128 + p] = -expm1f(-interval * log1pf(e));
            bf16x8 f0; bf16x4 f1;
            #pragma unroll
            for (int c = 0; c < 8; ++c) f0[c] = (__bf16)cc[c];
            #pragma unroll
            for (int c = 0; c < 4; ++c) f1[c] = (__bf16)cc[8+c];
            const int swz = (p & 7) << 4;
            *reinterpret_cast<bf16x8*>(smem + ((FB_FEAT_OFF + p*128 +  0) ^ swz)) = f0;
            *reinterpret_cast<bf16x4*>(smem + ((FB_FEAT_OFF + p*128 + 16) ^ swz)) = f1;
        } else {
            float vals[52];
            vals[0] = d0; vals[1] = d1; vals[2] = d2;
            #pragma unroll
            for (int i = 0; i < 3; ++i) {
                const float di = (i == 0) ? d0 : ((i == 1) ? d1 : d2);
                #pragma unroll
                for (int j = 0; j < 4; ++j) {
                    const float a = di * (float)(1 << j);
                    vals[3  + i*4 + j] = sinf(a);
                    vals[15 + i*4 + j] = cosf(a);
                }
            }
            #pragma unroll
            for (int c = 27; c < 52; ++c) vals[c] = 0.0f;
            const int swz = (p & 7) << 4;
            #pragma unroll
            for (int i = 0; i < 13; ++i) {
                bf16x4 v4;
                #pragma unroll
                for (int r = 0; r < 4; ++r) v4[r] = (__bf16)vals[i*4 + r];
                *reinterpret_cast<bf16x4*>(smem + ((FB_FEAT_OFF + p*128 + 24 + i*8) ^ swz)) = v4;
            }
        }
    }
    __syncthreads();
    const int lane = tid & 63;
    const int wid  = tid >> 6;
    const int lr   = lane & 15;
    const int lk   = lane >> 4;
    {
        bf16x8 bf[2][2];
        #pragma unroll
        for (int rt = 0; rt < 2; ++rt)
            #pragma unroll
            for (int ks = 0; ks < 2; ++ks) {
                const int pt = wid*32 + rt*16 + lr;
                int a = FB_FEAT_OFF + pt*128 + ks*64 + lk*16; a ^= (pt & 7) << 4;
                bf[rt][ks] = *reinterpret_cast<const bf16x8*>(smem + a);
            }
        __syncthreads();
        f32x4 acc1[2][8];
        #pragma unroll
        for (int rt = 0; rt < 2; ++rt)
            #pragma unroll
            for (int ct = 0; ct < 8; ++ct) acc1[rt][ct] = (f32x4){0.f,0.f,0.f,0.f};
        #pragma unroll
        for (int ct = 0; ct < 8; ++ct) {
            const bf16x8 aw0 = wf[(ct*2 + 0)*64 + lane];
            const bf16x8 aw1 = wf[(ct*2 + 1)*64 + lane];
            #pragma unroll
            for (int rt = 0; rt < 2; ++rt) {
                acc1[rt][ct] = __builtin_amdgcn_mfma_f32_16x16x32_bf16(aw0, bf[rt][0], acc1[rt][ct], 0, 0, 0);
                acc1[rt][ct] = __builtin_amdgcn_mfma_f32_16x16x32_bf16(aw1, bf[rt][1], acc1[rt][ct], 0, 0, 0);
            }
        }
        #pragma unroll
        for (int ct = 0; ct < 8; ++ct) {
            const f32x4 b1v = *reinterpret_cast<const f32x4*>(g_b1 + ct*16 + lk*4);
            #pragma unroll
            for (int rt = 0; rt < 2; ++rt) {
                const int pt = wid*32 + rt*16 + lr;
                bf16x4 hv;
                #pragma unroll
                for (int r = 0; r < 4; ++r)
                    hv[r] = (__bf16)fmaxf(acc1[rt][ct][r] + b1v[r], 0.0f);
                int a = FB_H1_OFF + pt*256 + ct*32 + lk*8; a ^= (pt & 7) << 4;
                *reinterpret_cast<bf16x4*>(smem + a) = hv;
            }
        }
    }
    __syncthreads();
    const int wr = wid >> 1, wc = wid & 1;
    f32x4 acc2[4][4];
    #pragma unroll
    for (int rt = 0; rt < 4; ++rt)
        #pragma unroll
        for (int ct = 0; ct < 4; ++ct) acc2[rt][ct] = (f32x4){0.f,0.f,0.f,0.f};
    #pragma unroll
    for (int ks = 0; ks < 4; ++ks) {
        bf16x8 a2[4];
        #pragma unroll
        for (int rt = 0; rt < 4; ++rt) {
            const int pt = wr*64 + rt*16 + lr;
            int a = FB_H1_OFF + pt*256 + ks*64 + lk*16; a ^= (pt & 7) << 4;
            a2[rt] = *reinterpret_cast<const bf16x8*>(smem + a);
        }
        #pragma unroll
        for (int ct = 0; ct < 4; ++ct) {
            const int ctg = wc*4 + ct;
            const bf16x8 b2f = wf[1024 + (ctg*4 + ks)*64 + lane];
            #pragma unroll
            for (int rt = 0; rt < 4; ++rt)
                acc2[rt][ct] = __builtin_amdgcn_mfma_f32_16x16x32_bf16(a2[rt], b2f, acc2[rt][ct], 0, 0, 0);
        }
    }
    __syncthreads();
    {
        float b2v[4], w30[4], w31[4], w32[4];
        #pragma unroll
        for (int ct = 0; ct < 4; ++ct) {
            const int n2 = wc*64 + ct*16 + lr;
            b2v[ct] = g_b2[n2];
            w30[ct] = g_w3[n2*3 + 0];
            w31[ct] = g_w3[n2*3 + 1];
            w32[ct] = g_w3[n2*3 + 2];
        }
        #pragma unroll
        for (int rt = 0; rt < 4; ++rt)
            #pragma unroll
            for (int r = 0; r < 4; ++r) {
                float s0 = 0.f, s1 = 0.f, s2 = 0.f;
                #pragma unroll
                for (int ct = 0; ct < 4; ++ct) {
                    const float v = fmaxf(acc2[rt][ct][r] + b2v[ct], 0.0f);
                    s0 = fmaf(v, w30[ct], s0);
                    s1 = fmaf(v, w31[ct], s1);
                    s2 = fmaf(v, w32[ct], s2);
                }
                #pragma unroll
                for (int off = 1; off < 16; off <<= 1) {
                    s0 += __shfl_xor(s0, off);
                    s1 += __shfl_xor(s1, off);
                    s2 += __shfl_xor(s2, off);
                }
                if (lr == 0) {
                    const int pt = wr*64 + rt*16 + lk*4 + r;
                    const int base = FB_PRGB_OFF/4 + (wc*128 + pt)*3;
                    smf[base + 0] = s0;
                    smf[base + 1] = s1;
                    smf[base + 2] = s2;
                }
            }
    }
    __syncthreads();
    if (tid < 128) {
        const int p = tid;
        const float s0 = smf[p*3 + 0] + smf[(128 + p)*3 + 0] + g_b3[0];
        const float s1 = smf[p*3 + 1] + smf[(128 + p)*3 + 1] + g_b3[1];
        const float s2 = smf[p*3 + 2] + smf[(128 + p)*3 + 2] + g_b3[2];
        const int pt = ray*128 + p;
        out_rgb[pt*3 + 0] = 1.0f / (1.0f + expf(-s0));
        out_rgb[pt*3 + 1] = 1.0f / (1.0f + expf(-s1));
        out_rgb[pt*3 + 2] = 1.0f / (1.0f + expf(-s2));
    }
}

extern "C" void kernel_launch(void* const* d_in, const int* in_sizes, int n_in,
                              void* d_out, int out_size, void* d_ws, size_t ws_size,
                              hipStream_t stream)
{
    const float* g_org = (const float*)d_in[0];
    const float* g_dir = (const float*)d_in[1];
    const float* g_len = (const float*)d_in[2];
    const float* g_gd  = (const float*)d_in[3];
    const float* g_gc  = (const float*)d_in[4];
    const float* g_w1  = (const float*)d_in[5];
    const float* g_b1  = (const float*)d_in[6];
    const float* g_w2  = (const float*)d_in[7];
    const float* g_b2  = (const float*)d_in[8];
    const float* g_w3  = (const float*)d_in[9];
    const float* g_b3  = (const float*)d_in[10];
    float* out = (float*)d_out;

    __bf16* wsb = (__bf16*)d_ws;
    bf16x8* pack = (bf16x8*)((char*)d_ws + PACK_B);

    if (ws_size >= NEED_FULL) {
        __bf16* feat = (__bf16*)((char*)d_ws + FEAT_B);
        dvgo_prep<<<4011, 256, 0, stream>>>(g_gd, g_gc, g_w1, g_w2, g_w3,
                                            pack, wsb, 3907);
        dvgo_gather<<<2048, 256, 0, stream>>>(g_org, g_dir, g_len, pack, feat, out);
        dvgo_mlp<<<4096, 256, 0, stream>>>((const bf16x8*)wsb, feat, g_dir,
                                           g_b1, g_b2, g_b3, out + 4096*128);
    } else if (ws_size >= NEED_PACK) {
        dvgo_prep<<<4011, 256, 0, stream>>>(g_gd, g_gc, g_w1, g_w2, g_w3,
                                            pack, wsb, 3907);
        dvgo_main<true><<<4096, 256, 0, stream>>>(g_org, g_dir, g_len, g_gd, g_gc,
                                                  g_b1, g_b2, g_w3, g_b3,
                                                  (const bf16x8*)wsb, pack,
                                                  out, out + 4096*128);
    } else {
        dvgo_prep<<<104, 256, 0, stream>>>(g_gd, g_gc, g_w1, g_w2, g_w3,
                                           pack, wsb, 0);
        dvgo_main<false><<<4096, 256, 0, stream>>>(g_org, g_dir, g_len, g_gd, g_gc,
                                                   g_b1, g_b2, g_w3, g_b3,
                                                   (const bf16x8*)wsb, nullptr,
                                                   out, out + 4096*128);
    }
}